// Round 1
// baseline (568.390 us; speedup 1.0000x reference)
//
#include <hip/hip_runtime.h>

#define D 64
#define K 5
#define LK 8                  // per-lane candidate list length
#define GK 12                 // global candidates rescored per row
#define NTILES 625            // 10000 / 16 exactly
#define PREPBLK 352           // covers 90112 >= 80000 repack + 10000 norm threads
#define NZBLK 4096            // zero-stream blocks
typedef unsigned int u32;
typedef unsigned long long u64;
typedef __bf16 bf16x8 __attribute__((ext_vector_type(8)));
typedef float  f32x4v __attribute__((ext_vector_type(4)));

// v_med3_u32 (GCN3+; no HIP builtin)
__device__ __forceinline__ u32 med3u(u32 a, u32 b, u32 c) {
    u32 r;
    asm("v_med3_u32 %0, %1, %2, %3" : "=v"(r) : "v"(a), "v"(b), "v"(c));
    return r;
}

// ---- u32 key: [31:14] = top bits of FULL monotone fp32 map, [13:0] = ~idx.
// bigger key == (bigger value, then lower idx). ----
__device__ __forceinline__ u32 pack32(float v, int idx) {
    u32 u = __float_as_uint(v);
    u ^= ((u32)((int)u >> 31)) | 0x80000000u;
    return (u & 0xFFFFC000u) | ((~(u32)idx) & 0x3FFFu);
}
__device__ __forceinline__ int idx32(u32 key) { return (int)((~key) & 0x3FFFu); }

// exact final key (value, then lower idx)
__device__ __forceinline__ u64 packKV(float v, int idx) {
    u32 u = __float_as_uint(v);
    u ^= ((u32)((int)u >> 31)) | 0x80000000u;
    return ((u64)u << 32) | (u32)(~idx);
}
__device__ __forceinline__ float unpackV(u64 key) {
    u32 hu = (u32)(key >> 32);
    return (hu & 0x80000000u) ? __uint_as_float(hu & 0x7fffffffu)
                              : __uint_as_float(~hu);
}

// branchless merge of two sorted-desc lists, keep first LO into a[]
template<int LO, int LA, int LB, typename T>
__device__ __forceinline__ void mergeKeep(T a[LA], const T b[LB]) {
    T A[LA], B[LB], out[LO];
#pragma unroll
    for (int i = 0; i < LA; ++i) A[i] = a[i];
#pragma unroll
    for (int i = 0; i < LB; ++i) B[i] = b[i];
#pragma unroll
    for (int m = 0; m < LO; ++m) {
        bool ta = A[0] >= B[0];
        out[m] = ta ? A[0] : B[0];
#pragma unroll
        for (int i = 0; i < LA - 1; ++i) A[i] = ta ? A[i + 1] : A[i];
        A[LA - 1] = ta ? (T)0 : A[LA - 1];
#pragma unroll
        for (int i = 0; i < LB - 1; ++i) B[i] = ta ? B[i] : B[i + 1];
        B[LB - 1] = ta ? B[LB - 1] : (T)0;
    }
#pragma unroll
    for (int m = 0; m < LO; ++m) a[m] = out[m];
}

// ---------------------------------------------------------------------------
// Fused prep + pure zero stream.
// Blocks [0, PREPBLK): repack x into MFMA-fragment order + row norms.
//   xbA[tile][khalf][lane][8 bf16]: lane = q*16+r holds x[tile*16+r][kh*32+q*8..+8).
// Blocks [PREPBLK, PREPBLK+NZBLK): zero the 400 MB output in contiguous
//   fill-shaped chunks (nothing else in these blocks' vmcnt queues).
// ---------------------------------------------------------------------------
__global__ __launch_bounds__(256) void prep_zero(
    const float* __restrict__ x, __bf16* __restrict__ xbA, float* __restrict__ xxf,
    int N, float* __restrict__ outZ, long long totalF4, int f4PerZ)
{
    const int bx = blockIdx.x;
    const int tid = threadIdx.x;

    if (bx < PREPBLK) {
        int g = bx * 256 + tid;
        const int REPACK = NTILES * 2 * 64;          // 80000
        if (g < REPACK) {
            int tile = g >> 7;
            int rem  = g & 127;
            int kh   = rem >> 6;
            int lane = rem & 63;
            int q = lane >> 4, r = lane & 15;
            int row = tile * 16 + r;
            int k0  = kh * 32 + q * 8;
            const float4* p = (const float4*)(x + (size_t)row * D + k0);
            float4 v0 = p[0], v1 = p[1];
            bf16x8 o;
            o[0] = (__bf16)v0.x; o[1] = (__bf16)v0.y; o[2] = (__bf16)v0.z; o[3] = (__bf16)v0.w;
            o[4] = (__bf16)v1.x; o[5] = (__bf16)v1.y; o[6] = (__bf16)v1.z; o[7] = (__bf16)v1.w;
            ((bf16x8*)xbA)[g] = o;
            return;
        }
        int i = g - REPACK;
        if (i >= N) return;
        const float4* p = (const float4*)(x + (size_t)i * D);
        float s = 0.f;
#pragma unroll
        for (int t = 0; t < 16; ++t) {
            float4 v = p[t];
            s += v.x * v.x + v.y * v.y + v.z * v.z + v.w * v.w;
        }
        xxf[i] = s;
        return;
    }

    // ---------------- zero stream ----------------
    int zid = bx - PREPBLK;
    long long s = (long long)zid * f4PerZ;
    long long e = s + f4PerZ; if (e > totalF4) e = totalF4;
    const f32x4v z = {0.f, 0.f, 0.f, 0.f};
    for (long long i = s + tid; i < e; i += 256)
        __builtin_nontemporal_store(z, (f32x4v*)(outZ + 4 * i));
}

// ---------------------------------------------------------------------------
// One block per 16-row tile (625 blocks). All 4 waves share the B fragments;
// each wave scans one residue class of the 625 column tiles (1-deep pipelined
// A prefetch), keeping a per-lane top-8 via the med3 insertion network.
// Per-row combine: quad butterfly -> LDS -> 4-lane merge to top-12 -> exact
// fp32 rescore (3 cands/lane) -> exact u64 top-5 -> inline symmetric atomic
// scatter (out is fully zeroed by prep_zero, which precedes on the stream).
// ---------------------------------------------------------------------------
__global__ __launch_bounds__(256) void knn_select(
    const __bf16* __restrict__ xbA, const float* __restrict__ xxf,
    const float* __restrict__ x, int N, float* __restrict__ out)
{
    const int rb   = blockIdx.x;                 // rows rb*16 .. rb*16+15
    const int tid  = threadIdx.x;
    const int lane = tid & 63;
    const int wave = tid >> 6;
    const int q    = lane >> 4;                  // col quad

    const bf16x8* fb = (const bf16x8*)xbA;       // 128 fragments per tile
    const bf16x8 B0 = fb[rb * 128 + lane];
    const bf16x8 B1 = fb[rb * 128 + 64 + lane];

    const int t0 = wave ^ 3;                     // wave0 gets residue 3 (156 tiles):
                                                 // it also runs the stage-2 tail
    const bf16x8* ap = fb + (size_t)t0 * 128 + lane;
    const float*  xcp = xxf + t0 * 16 + q * 4;
    int cbase = t0 * 16 + q * 4;

    u32 L[LK];
#pragma unroll
    for (int m = 0; m < LK; ++m) L[m] = 0u;      // 0 < any real packed key

    // 1-deep software pipeline: prefetch next tile's A fragments + norms.
    // Final prefetch runs <=4 tiles past the table; ws layout pads for it.
    bf16x8 A0 = ap[0];
    bf16x8 A1 = ap[64];
    f32x4v xc = *(const f32x4v*)xcp;

    for (int t = t0; t < NTILES; t += 4) {
        ap += 512; xcp += 64;
        const bf16x8 nA0 = ap[0];
        const bf16x8 nA1 = ap[64];
        const f32x4v nxc = *(const f32x4v*)xcp;

        f32x4v acc = {0.f, 0.f, 0.f, 0.f};
        acc = __builtin_amdgcn_mfma_f32_16x16x32_bf16(A0, B0, acc, 0, 0, 0);
        acc = __builtin_amdgcn_mfma_f32_16x16x32_bf16(A1, B1, acc, 0, 0, 0);

#pragma unroll
        for (int v = 0; v < 4; ++v) {
            float dk = fmaf(-0.5f, xc[v], acc[v]);   // ordering == distance ordering
            u32 key = pack32(dk, cbase + v);
            u32 n0 = max(L[0], key);
            u32 n1 = med3u(L[0], L[1], key);
            u32 n2 = med3u(L[1], L[2], key);
            u32 n3 = med3u(L[2], L[3], key);
            u32 n4 = med3u(L[3], L[4], key);
            u32 n5 = med3u(L[4], L[5], key);
            u32 n6 = med3u(L[5], L[6], key);
            u32 n7 = med3u(L[6], L[7], key);
            L[0]=n0; L[1]=n1; L[2]=n2; L[3]=n3; L[4]=n4; L[5]=n5; L[6]=n6; L[7]=n7;
        }
        cbase += 64;
        A0 = nA0; A1 = nA1; xc = nxc;
    }

    // butterfly merge across the 4 quads sharing a row -> per-wave top-8/row
#pragma unroll
    for (int mask = 16; mask <= 32; mask <<= 1) {
        u32 P[LK];
#pragma unroll
        for (int m = 0; m < LK; ++m) P[m] = (u32)__shfl_xor((int)L[m], mask);
        mergeKeep<LK, LK, LK, u32>(L, P);
    }

    __shared__ u32 lsd[4][16][LK];               // 2 KB
    if (lane < 16) {
#pragma unroll
        for (int m = 0; m < LK; ++m) lsd[wave][lane][m] = L[m];
    }
    __syncthreads();
    if (wave != 0) return;

    // ---- stage 2 (wave 0): 4 lanes per row ----
    const int sub = lane & 3;
    const int rl  = lane >> 2;
    const int row = rb * 16 + rl;
    const bool vrow = (row < N);
    const int rr = vrow ? row : 0;

    u32 cur[GK];
#pragma unroll
    for (int m = 0; m < LK; ++m) cur[m] = lsd[sub][rl][m];
#pragma unroll
    for (int m = LK; m < GK; ++m) cur[m] = 0u;
#pragma unroll
    for (int mask = 1; mask <= 2; mask <<= 1) {
        u32 P[GK];
#pragma unroll
        for (int m = 0; m < GK; ++m) P[m] = (u32)__shfl_xor((int)cur[m], mask);
        mergeKeep<GK, GK, GK, u32>(cur, P);
    }

    // exact fp32 rescore of my 3 candidates
    const float nxi = xxf[rr];
    int   cj[3]; bool cval[3];
    float d[3] = {0.f, 0.f, 0.f};
    const f32x4v* pj[3];
#pragma unroll
    for (int c = 0; c < 3; ++c) {
        int j = idx32(cur[sub * 3 + c]);
        cval[c] = (j < N) && (cur[sub * 3 + c] != 0u);
        cj[c] = cval[c] ? j : 0;
        pj[c] = (const f32x4v*)(x + (size_t)cj[c] * D);
    }
    const f32x4v* xip = (const f32x4v*)(x + (size_t)rr * D);
#pragma unroll
    for (int t = 0; t < 16; ++t) {
        const f32x4v xv = xip[t];
#pragma unroll
        for (int c = 0; c < 3; ++c) {
            const f32x4v pv = pj[c][t];
            d[c] = fmaf(xv[0], pv[0], d[c]);
            d[c] = fmaf(xv[1], pv[1], d[c]);
            d[c] = fmaf(xv[2], pv[2], d[c]);
            d[c] = fmaf(xv[3], pv[3], d[c]);
        }
    }
    u64 F[K];
#pragma unroll
    for (int c = 0; c < 3; ++c) {
        float val = 2.f * d[c] - nxi - xxf[cj[c]];
        F[c] = cval[c] ? packKV(val, cj[c]) : 0ull;
    }
    F[3] = 0ull; F[4] = 0ull;
    // sort first 3 desc
    { u64 a0=F[0],a1=F[1],a2=F[2];
      if (a0 < a1) { u64 t0s=a0; a0=a1; a1=t0s; }
      if (a1 < a2) { u64 t0s=a1; a1=a2; a2=t0s; }
      if (a0 < a1) { u64 t0s=a0; a0=a1; a1=t0s; }
      F[0]=a0; F[1]=a1; F[2]=a2; }
#pragma unroll
    for (int mask = 1; mask <= 2; mask <<= 1) {
        u64 P[K];
#pragma unroll
        for (int m = 0; m < K; ++m) P[m] = __shfl_xor(F[m], mask);
        mergeKeep<K, K, K, u64>(F, P);
    }

    // inline symmetric scatter (out fully zeroed by prep_zero)
    if (sub == 0 && vrow) {
#pragma unroll
        for (int m = 0; m < K; ++m) {
            int j = (int)(~(u32)F[m]);
            if ((unsigned)j < (unsigned)N && j != row) {
                float v = unpackV(F[m]);
                atomicAdd(out + (size_t)row * N + j, v);
                atomicAdd(out + (size_t)j * N + row, v);
            }
        }
    }
}

// ---------------------------------------------------------------------------
extern "C" void kernel_launch(void* const* d_in, const int* in_sizes, int n_in,
                              void* d_out, int out_size, void* d_ws, size_t ws_size,
                              hipStream_t stream) {
    const float* x = (const float*)d_in[0];
    const int N = in_sizes[0] / D;          // 10000
    float* out = (float*)d_out;

    // Workspace: xbA[625*128 fragments * 16B = 1.28 MB] + 32 KB prefetch pad |
    //            xxf[N] f32 + pad. Total ~1.42 MB.
    const size_t oXB = 0;
    const size_t oXX = 0x150000;            // 1.3125 MB
    __bf16* xbA = (__bf16*)((char*)d_ws + oXB);
    float*  xxf = (float*)((char*)d_ws + oXX);

    long long totalF4 = (long long)out_size / 4;             // 25e6
    int f4PerZ = (int)((totalF4 + NZBLK - 1) / NZBLK);       // 6104

    prep_zero<<<PREPBLK + NZBLK, 256, 0, stream>>>(x, xbA, xxf, N, out, totalF4, f4PerZ);
    knn_select<<<NTILES, 256, 0, stream>>>(xbA, xxf, x, N, out);
}

// Round 2
// 547.103 us; speedup vs baseline: 1.0389x; 1.0389x over previous
//
#include <hip/hip_runtime.h>

#define D 64
#define K 5
#define LK 8                  // per-lane candidate list length
#define GK 12                 // global candidates rescored per row
#define NTILES 625            // 10000 / 16 exactly
#define PREPBLK 352           // covers 90112 >= 80000 repack + 10000 norm threads
#define NSEL 625              // select blocks (one per 16-row tile)
#define NZB  512              // zero-stream blocks
#define NW   8                // waves per select block
typedef unsigned int u32;
typedef unsigned long long u64;
typedef __bf16 bf16x8 __attribute__((ext_vector_type(8)));
typedef float  f32x4v __attribute__((ext_vector_type(4)));

// v_med3_u32 (GCN3+; no HIP builtin)
__device__ __forceinline__ u32 med3u(u32 a, u32 b, u32 c) {
    u32 r;
    asm("v_med3_u32 %0, %1, %2, %3" : "=v"(r) : "v"(a), "v"(b), "v"(c));
    return r;
}

// ---- u32 key: [31:14] = top bits of FULL monotone fp32 map, [13:0] = ~idx.
// bigger key == (bigger value, then lower idx). ----
__device__ __forceinline__ u32 pack32(float v, int idx) {
    u32 u = __float_as_uint(v);
    u ^= ((u32)((int)u >> 31)) | 0x80000000u;
    return (u & 0xFFFFC000u) | ((~(u32)idx) & 0x3FFFu);
}
__device__ __forceinline__ int idx32(u32 key) { return (int)((~key) & 0x3FFFu); }

// exact final key (value, then lower idx)
__device__ __forceinline__ u64 packKV(float v, int idx) {
    u32 u = __float_as_uint(v);
    u ^= ((u32)((int)u >> 31)) | 0x80000000u;
    return ((u64)u << 32) | (u32)(~idx);
}
__device__ __forceinline__ float unpackV(u64 key) {
    u32 hu = (u32)(key >> 32);
    return (hu & 0x80000000u) ? __uint_as_float(hu & 0x7fffffffu)
                              : __uint_as_float(~hu);
}

// branchless merge of two sorted-desc lists, keep first LO into a[]
template<int LO, int LA, int LB, typename T>
__device__ __forceinline__ void mergeKeep(T a[LA], const T b[LB]) {
    T A[LA], B[LB], out[LO];
#pragma unroll
    for (int i = 0; i < LA; ++i) A[i] = a[i];
#pragma unroll
    for (int i = 0; i < LB; ++i) B[i] = b[i];
#pragma unroll
    for (int m = 0; m < LO; ++m) {
        bool ta = A[0] >= B[0];
        out[m] = ta ? A[0] : B[0];
#pragma unroll
        for (int i = 0; i < LA - 1; ++i) A[i] = ta ? A[i + 1] : A[i];
        A[LA - 1] = ta ? (T)0 : A[LA - 1];
#pragma unroll
        for (int i = 0; i < LB - 1; ++i) B[i] = ta ? B[i] : B[i + 1];
        B[LB - 1] = ta ? B[LB - 1] : (T)0;
    }
#pragma unroll
    for (int m = 0; m < LO; ++m) a[m] = out[m];
}

// ---------------------------------------------------------------------------
// Prep: repack x into MFMA-fragment order + row norms.
// xbA[tile][khalf][lane][8 bf16]: lane = q*16+r holds x[tile*16+r][kh*32+q*8..+8).
// ---------------------------------------------------------------------------
__global__ __launch_bounds__(256) void prep(
    const float* __restrict__ x, __bf16* __restrict__ xbA, float* __restrict__ xxf, int N)
{
    int g = blockIdx.x * 256 + threadIdx.x;
    const int REPACK = NTILES * 2 * 64;          // 80000
    if (g < REPACK) {
        int tile = g >> 7;
        int rem  = g & 127;
        int kh   = rem >> 6;
        int lane = rem & 63;
        int q = lane >> 4, r = lane & 15;
        int row = tile * 16 + r;
        int k0  = kh * 32 + q * 8;
        const float4* p = (const float4*)(x + (size_t)row * D + k0);
        float4 v0 = p[0], v1 = p[1];
        bf16x8 o;
        o[0] = (__bf16)v0.x; o[1] = (__bf16)v0.y; o[2] = (__bf16)v0.z; o[3] = (__bf16)v0.w;
        o[4] = (__bf16)v1.x; o[5] = (__bf16)v1.y; o[6] = (__bf16)v1.z; o[7] = (__bf16)v1.w;
        ((bf16x8*)xbA)[g] = o;
        return;
    }
    int i = g - REPACK;
    if (i >= N) return;
    const float4* p = (const float4*)(x + (size_t)i * D);
    float s = 0.f;
#pragma unroll
    for (int t = 0; t < 16; ++t) {
        float4 v = p[t];
        s += v.x * v.x + v.y * v.y + v.z * v.z + v.w * v.w;
    }
    xxf[i] = s;
}

// ---------------------------------------------------------------------------
// Fused zero + select, 512-thread blocks.
// Blocks [0, NZB): NT-stream the 400 MB output zero (nothing else in their
//   vmcnt queues; co-resident with select blocks -> write stream overlaps
//   compute at the scheduler level).
// Blocks [NZB, NZB+NSEL): one 16-row tile each. 8 waves share the B
//   fragments; wave w scans column-tile residue class (7-w) mod 8 with a
//   1-deep pipelined A prefetch, keeping per-lane top-8 via med3 network.
//   Combine: quad butterfly -> LDS (8 lists/row) -> wave0: 4 lanes/row merge
//   to global top-12 -> exact fp32 rescore (3 cands/lane) -> exact u64 top-5
//   -> write to ws5 (NO out access -> no race with the zero stream).
// ---------------------------------------------------------------------------
__global__ __launch_bounds__(512) void zero_select(
    const __bf16* __restrict__ xbA, const float* __restrict__ xxf,
    const float* __restrict__ x, int N,
    float* __restrict__ outZ, long long totalF4, int f4PerZ,
    u64* __restrict__ ws5)
{
    const int bx  = blockIdx.x;
    const int tid = threadIdx.x;

    if (bx < NZB) {
        // ---------------- zero stream ----------------
        long long s = (long long)bx * f4PerZ;
        long long e = s + f4PerZ; if (e > totalF4) e = totalF4;
        const f32x4v z = {0.f, 0.f, 0.f, 0.f};
        for (long long i = s + tid; i < e; i += 512)
            __builtin_nontemporal_store(z, (f32x4v*)(outZ + 4 * i));
        return;
    }

    // ---------------- select ----------------
    const int rb   = bx - NZB;                   // rows rb*16 .. rb*16+15
    const int lane = tid & 63;
    const int wave = tid >> 6;                   // 0..7
    const int q    = lane >> 4;                  // col quad

    const bf16x8* fb = (const bf16x8*)xbA;       // 128 fragments per tile
    const bf16x8 B0 = fb[rb * 128 + lane];
    const bf16x8 B1 = fb[rb * 128 + 64 + lane];

    const int t0 = 7 - wave;                     // wave0 -> residue 7 (78 tiles):
                                                 // it also runs the stage-2 tail
    const bf16x8* ap = fb + (size_t)t0 * 128 + lane;
    const float*  xcp = xxf + t0 * 16 + q * 4;
    int cbase = t0 * 16 + q * 4;

    u32 L[LK];
#pragma unroll
    for (int m = 0; m < LK; ++m) L[m] = 0u;      // 0 < any real packed key

    // 1-deep software pipeline: prefetch next tile's A fragments + norms.
    // Final prefetch runs <=8 tiles past the table; ws layout pads for it.
    bf16x8 A0 = ap[0];
    bf16x8 A1 = ap[64];
    f32x4v xc = *(const f32x4v*)xcp;

    for (int t = t0; t < NTILES; t += NW) {
        ap += NW * 128; xcp += NW * 16;
        const bf16x8 nA0 = ap[0];
        const bf16x8 nA1 = ap[64];
        const f32x4v nxc = *(const f32x4v*)xcp;

        f32x4v acc = {0.f, 0.f, 0.f, 0.f};
        acc = __builtin_amdgcn_mfma_f32_16x16x32_bf16(A0, B0, acc, 0, 0, 0);
        acc = __builtin_amdgcn_mfma_f32_16x16x32_bf16(A1, B1, acc, 0, 0, 0);

#pragma unroll
        for (int v = 0; v < 4; ++v) {
            float dk = fmaf(-0.5f, xc[v], acc[v]);   // ordering == distance ordering
            u32 key = pack32(dk, cbase + v);
            u32 n0 = max(L[0], key);
            u32 n1 = med3u(L[0], L[1], key);
            u32 n2 = med3u(L[1], L[2], key);
            u32 n3 = med3u(L[2], L[3], key);
            u32 n4 = med3u(L[3], L[4], key);
            u32 n5 = med3u(L[4], L[5], key);
            u32 n6 = med3u(L[5], L[6], key);
            u32 n7 = med3u(L[6], L[7], key);
            L[0]=n0; L[1]=n1; L[2]=n2; L[3]=n3; L[4]=n4; L[5]=n5; L[6]=n6; L[7]=n7;
        }
        cbase += NW * 16;
        A0 = nA0; A1 = nA1; xc = nxc;
    }

    // butterfly merge across the 4 quads sharing a row -> per-wave top-8/row
#pragma unroll
    for (int mask = 16; mask <= 32; mask <<= 1) {
        u32 P[LK];
#pragma unroll
        for (int m = 0; m < LK; ++m) P[m] = (u32)__shfl_xor((int)L[m], mask);
        mergeKeep<LK, LK, LK, u32>(L, P);
    }

    __shared__ u32 lsd[NW][16][LK];              // 4 KB
    if (lane < 16) {
#pragma unroll
        for (int m = 0; m < LK; ++m) lsd[wave][lane][m] = L[m];
    }
    __syncthreads();
    if (wave != 0) return;

    // ---- stage 2 (wave 0): 4 lanes per row, each merges 2 wave-lists ----
    const int sub = lane & 3;
    const int rl  = lane >> 2;
    const int row = rb * 16 + rl;
    const bool vrow = (row < N);
    const int rr = vrow ? row : 0;

    u32 cur[GK];
#pragma unroll
    for (int m = 0; m < LK; ++m) cur[m] = lsd[2 * sub][rl][m];
#pragma unroll
    for (int m = LK; m < GK; ++m) cur[m] = 0u;
    {
        u32 b[LK];
#pragma unroll
        for (int m = 0; m < LK; ++m) b[m] = lsd[2 * sub + 1][rl][m];
        mergeKeep<GK, GK, LK, u32>(cur, b);
    }
#pragma unroll
    for (int mask = 1; mask <= 2; mask <<= 1) {
        u32 P[GK];
#pragma unroll
        for (int m = 0; m < GK; ++m) P[m] = (u32)__shfl_xor((int)cur[m], mask);
        mergeKeep<GK, GK, GK, u32>(cur, P);
    }

    // exact fp32 rescore of my 3 candidates
    const float nxi = xxf[rr];
    int   cj[3]; bool cval[3];
    float d[3] = {0.f, 0.f, 0.f};
    const f32x4v* pj[3];
#pragma unroll
    for (int c = 0; c < 3; ++c) {
        int j = idx32(cur[sub * 3 + c]);
        cval[c] = (j < N) && (cur[sub * 3 + c] != 0u);
        cj[c] = cval[c] ? j : 0;
        pj[c] = (const f32x4v*)(x + (size_t)cj[c] * D);
    }
    const f32x4v* xip = (const f32x4v*)(x + (size_t)rr * D);
#pragma unroll
    for (int t = 0; t < 16; ++t) {
        const f32x4v xv = xip[t];
#pragma unroll
        for (int c = 0; c < 3; ++c) {
            const f32x4v pv = pj[c][t];
            d[c] = fmaf(xv[0], pv[0], d[c]);
            d[c] = fmaf(xv[1], pv[1], d[c]);
            d[c] = fmaf(xv[2], pv[2], d[c]);
            d[c] = fmaf(xv[3], pv[3], d[c]);
        }
    }
    u64 F[K];
#pragma unroll
    for (int c = 0; c < 3; ++c) {
        float val = 2.f * d[c] - nxi - xxf[cj[c]];
        F[c] = cval[c] ? packKV(val, cj[c]) : 0ull;
    }
    F[3] = 0ull; F[4] = 0ull;
    // sort first 3 desc
    { u64 a0=F[0],a1=F[1],a2=F[2];
      if (a0 < a1) { u64 t0s=a0; a0=a1; a1=t0s; }
      if (a1 < a2) { u64 t0s=a1; a1=a2; a2=t0s; }
      if (a0 < a1) { u64 t0s=a0; a0=a1; a1=t0s; }
      F[0]=a0; F[1]=a1; F[2]=a2; }
#pragma unroll
    for (int mask = 1; mask <= 2; mask <<= 1) {
        u64 P[K];
#pragma unroll
        for (int m = 0; m < K; ++m) P[m] = __shfl_xor(F[m], mask);
        mergeKeep<K, K, K, u64>(F, P);
    }

    if (sub == 0 && vrow) {
#pragma unroll
        for (int m = 0; m < K; ++m) ws5[(size_t)row * K + m] = F[m];
    }
}

// ---------------------------------------------------------------------------
// Scatter: one thread per row; symmetric atomic adds (out fully zeroed by
// zero_select, which precedes on the stream).
// ---------------------------------------------------------------------------
__global__ __launch_bounds__(256) void scatter(
    const u64* __restrict__ ws5, float* __restrict__ out, int N)
{
    int row = blockIdx.x * 256 + threadIdx.x;
    if (row >= N) return;
#pragma unroll
    for (int m = 0; m < K; ++m) {
        u64 f = ws5[(size_t)row * K + m];
        int j = (int)(~(u32)f);
        if ((unsigned)j < (unsigned)N && j != row) {
            float v = unpackV(f);
            atomicAdd(out + (size_t)row * N + j, v);
            atomicAdd(out + (size_t)j * N + row, v);
        }
    }
}

// ---------------------------------------------------------------------------
extern "C" void kernel_launch(void* const* d_in, const int* in_sizes, int n_in,
                              void* d_out, int out_size, void* d_ws, size_t ws_size,
                              hipStream_t stream) {
    const float* x = (const float*)d_in[0];
    const int N = in_sizes[0] / D;          // 10000
    float* out = (float*)d_out;

    // Workspace layout:
    //   xbA: 625*128 fragments * 16B = 1.28 MB, padded to 0x150000 (prefetch
    //        overruns read <= 8 tiles = 16 KB past the table)
    //   xxf: N f32 = 40 KB, padded to 64 KB (xc prefetch overruns ~0.5 KB)
    //   ws5: N*K u64 = 400 KB
    const size_t oXB = 0;
    const size_t oXX = 0x150000;
    const size_t oW5 = 0x160000;
    __bf16* xbA = (__bf16*)((char*)d_ws + oXB);
    float*  xxf = (float*)((char*)d_ws + oXX);
    u64*    ws5 = (u64*)((char*)d_ws + oW5);

    long long totalF4 = (long long)out_size / 4;             // 25e6
    int f4PerZ = (int)((totalF4 + NZB - 1) / NZB);           // 48829

    prep<<<PREPBLK, 256, 0, stream>>>(x, xbA, xxf, N);
    zero_select<<<NZB + NSEL, 512, 0, stream>>>(
        xbA, xxf, x, N, out, totalF4, f4PerZ, ws5);
    scatter<<<(N + 255) / 256, 256, 0, stream>>>(ws5, out, N);
}

// Round 3
// 452.446 us; speedup vs baseline: 1.2563x; 1.2092x over previous
//
#include <hip/hip_runtime.h>

#define D 64
#define K 5
#define LK 8                  // per-lane / per-split candidate list length
#define GK 12                 // global candidates rescored per row
#define NSPLIT 16
#define NTILES 625            // 10000 / 16 exactly
#define ROWBLK 157            // ceil(10000/64)
#define NCOMP (ROWBLK * NSPLIT)   // 2512 compute blocks
typedef unsigned int u32;
typedef unsigned long long u64;
typedef __bf16 bf16x8 __attribute__((ext_vector_type(8)));
typedef float  f32x4v __attribute__((ext_vector_type(4)));

// v_med3_u32 (GCN3+; no HIP builtin)
__device__ __forceinline__ u32 med3u(u32 a, u32 b, u32 c) {
    u32 r;
    asm("v_med3_u32 %0, %1, %2, %3" : "=v"(r) : "v"(a), "v"(b), "v"(c));
    return r;
}

// ---- u32 key: [31:14] = top bits of FULL monotone fp32 map, [13:0] = ~idx.
// bigger key == (bigger value, then lower idx). ----
__device__ __forceinline__ u32 pack32(float v, int idx) {
    u32 u = __float_as_uint(v);
    u ^= ((u32)((int)u >> 31)) | 0x80000000u;
    return (u & 0xFFFFC000u) | ((~(u32)idx) & 0x3FFFu);
}
__device__ __forceinline__ int idx32(u32 key) { return (int)((~key) & 0x3FFFu); }

// exact final key (value, then lower idx)
__device__ __forceinline__ u64 packKV(float v, int idx) {
    u32 u = __float_as_uint(v);
    u ^= ((u32)((int)u >> 31)) | 0x80000000u;
    return ((u64)u << 32) | (u32)(~idx);
}
__device__ __forceinline__ float unpackV(u64 key) {
    u32 hu = (u32)(key >> 32);
    return (hu & 0x80000000u) ? __uint_as_float(hu & 0x7fffffffu)
                              : __uint_as_float(~hu);
}

// branchless merge of two sorted-desc lists, keep first LO into a[]
template<int LO, int LA, int LB, typename T>
__device__ __forceinline__ void mergeKeep(T a[LA], const T b[LB]) {
    T A[LA], B[LB], out[LO];
#pragma unroll
    for (int i = 0; i < LA; ++i) A[i] = a[i];
#pragma unroll
    for (int i = 0; i < LB; ++i) B[i] = b[i];
#pragma unroll
    for (int m = 0; m < LO; ++m) {
        bool ta = A[0] >= B[0];
        out[m] = ta ? A[0] : B[0];
#pragma unroll
        for (int i = 0; i < LA - 1; ++i) A[i] = ta ? A[i + 1] : A[i];
        A[LA - 1] = ta ? (T)0 : A[LA - 1];
#pragma unroll
        for (int i = 0; i < LB - 1; ++i) B[i] = ta ? B[i] : B[i + 1];
        B[LB - 1] = ta ? B[LB - 1] : (T)0;
    }
#pragma unroll
    for (int m = 0; m < LO; ++m) a[m] = out[m];
}

// ---------------------------------------------------------------------------
// Prep: repack x into MFMA-fragment order + row norms.
// xbA[tile][khalf][lane][8 bf16]: lane = q*16+r holds x[tile*16+r][kh*32+q*8..+8).
// ---------------------------------------------------------------------------
__global__ __launch_bounds__(256) void prep(
    const float* __restrict__ x, __bf16* __restrict__ xbA, float* __restrict__ xxf, int N)
{
    int g = blockIdx.x * 256 + threadIdx.x;
    const int REPACK = NTILES * 2 * 64;          // 80000
    if (g < REPACK) {
        int tile = g >> 7;
        int rem  = g & 127;
        int kh   = rem >> 6;
        int lane = rem & 63;
        int q = lane >> 4, r = lane & 15;
        int row = tile * 16 + r;
        int k0  = kh * 32 + q * 8;
        const float4* p = (const float4*)(x + (size_t)row * D + k0);
        float4 v0 = p[0], v1 = p[1];
        bf16x8 o;
        o[0] = (__bf16)v0.x; o[1] = (__bf16)v0.y; o[2] = (__bf16)v0.z; o[3] = (__bf16)v0.w;
        o[4] = (__bf16)v1.x; o[5] = (__bf16)v1.y; o[6] = (__bf16)v1.z; o[7] = (__bf16)v1.w;
        ((bf16x8*)xbA)[g] = o;
        return;
    }
    int i = g - REPACK;
    if (i >= N) return;
    const float4* p = (const float4*)(x + (size_t)i * D);
    float s = 0.f;
#pragma unroll
    for (int t = 0; t < 16; ++t) {
        float4 v = p[t];
        s += v.x * v.x + v.y * v.y + v.z * v.z + v.w * v.w;
    }
    xxf[i] = s;
}

// ---------------------------------------------------------------------------
// Block-specialized (proven r0 structure): bx%6==0 -> PURE ZERO blocks
// (NT store stream only); the rest are PURE COMPUTE blocks. Interleaved
// dispatch order keeps both co-resident per CU from the start -> the write
// stream and compute truly overlap at the scheduler level.
// Compute changes vs r0 (latency attacks):
//   * 2-deep A/xc prefetch (L2 ~200cyc hidden under 2 iterations of compute)
//   * split accumulators: two independent MFMAs + one VALU add (breaks the
//     serial mfma->mfma dependency)
//   * __launch_bounds__(256,6): VGPR cap ~84 -> 6 waves/SIMD latency hiding
// ---------------------------------------------------------------------------
__global__ __launch_bounds__(256, 6) void topk_zero_mfma(
    const __bf16* __restrict__ xbA, const float* __restrict__ xxf, int N,
    u32* __restrict__ wsK, float* __restrict__ outZ, long long totalF4,
    int nZero, int f4PerZ)
{
    const int bx  = blockIdx.x;
    const int tid = threadIdx.x;

    if (bx % 6 == 0) {
        // ---------------- zero block ----------------
        int zid = bx / 6;
        if (zid >= nZero) return;
        long long s = (long long)zid * f4PerZ;
        long long e = s + f4PerZ; if (e > totalF4) e = totalF4;
        const f32x4v z = {0.f, 0.f, 0.f, 0.f};
        for (long long i = s + tid; i < e; i += 256)
            __builtin_nontemporal_store(z, (f32x4v*)(outZ + 4 * i));
        return;
    }

    // ---------------- compute block ----------------
    const int cid = bx - (bx / 6 + 1);           // dense index over non-zero blocks
    if (cid >= NCOMP) return;
    const int split = cid / ROWBLK;              // 0..15
    const int rb    = cid - split * ROWBLK;      // 0..156

    const int lane = tid & 63;
    const int wave = tid >> 6;
    const int l15  = lane & 15;
    const int q    = lane >> 4;                  // col quad
    const int r0 = rb * 64 + wave * 16;

    const bf16x8* fb = (const bf16x8*)xbA;       // fragment base, 128 per tile

    // B fragments: my 16-row tile (clamped for tail waves), held in regs
    int bt = r0 >> 4; if (bt > NTILES - 1) bt = NTILES - 1;
    const bf16x8 B0 = fb[bt * 128 + lane];
    const bf16x8 B1 = fb[bt * 128 + 64 + lane];

    // pointer-bumped loop state
    const bf16x8* ap = fb + (size_t)split * 128 + lane;
    const float* xcp = xxf + split * 16 + q * 4;
    int cbase = split * 16 + q * 4;
    const int apBump = NSPLIT * 128;             // 2048 fragments
    const int xcBump = NSPLIT * 16;              // 256 floats

    u32 L[LK];
#pragma unroll
    for (int m = 0; m < LK; ++m) L[m] = 0u;      // 0 < any real packed key

    // 2-deep software pipeline: prefetch reads run <=32 tiles past the
    // table; workspace layout pads for it (64 KB after xbA, 24 KB after xxf).
    bf16x8 A0a = ap[0];
    bf16x8 A1a = ap[64];
    f32x4v xca = *(const f32x4v*)xcp;
    ap += apBump; xcp += xcBump;
    bf16x8 A0b = ap[0];
    bf16x8 A1b = ap[64];
    f32x4v xcb = *(const f32x4v*)xcp;

    for (int t = split; t < NTILES; t += NSPLIT) {
        ap += apBump; xcp += xcBump;
        const bf16x8 nA0 = ap[0];
        const bf16x8 nA1 = ap[64];
        const f32x4v nxc = *(const f32x4v*)xcp;

        f32x4v acc0 = {0.f, 0.f, 0.f, 0.f};
        f32x4v acc1 = {0.f, 0.f, 0.f, 0.f};
        acc0 = __builtin_amdgcn_mfma_f32_16x16x32_bf16(A0a, B0, acc0, 0, 0, 0);
        acc1 = __builtin_amdgcn_mfma_f32_16x16x32_bf16(A1a, B1, acc1, 0, 0, 0);

        // full monotone key map + med3 insertion
#pragma unroll
        for (int v = 0; v < 4; ++v) {
            float dk = fmaf(-0.5f, xca[v], acc0[v] + acc1[v]);  // ordering == distance ordering
            u32 key = pack32(dk, cbase + v);
            u32 n0 = max(L[0], key);
            u32 n1 = med3u(L[0], L[1], key);
            u32 n2 = med3u(L[1], L[2], key);
            u32 n3 = med3u(L[2], L[3], key);
            u32 n4 = med3u(L[3], L[4], key);
            u32 n5 = med3u(L[4], L[5], key);
            u32 n6 = med3u(L[5], L[6], key);
            u32 n7 = med3u(L[6], L[7], key);
            L[0]=n0; L[1]=n1; L[2]=n2; L[3]=n3; L[4]=n4; L[5]=n5; L[6]=n6; L[7]=n7;
        }
        cbase += xcBump;
        A0a = A0b; A1a = A1b; xca = xcb;
        A0b = nA0; A1b = nA1; xcb = nxc;
    }

    // butterfly merge across the 4 quads sharing a row
#pragma unroll
    for (int mask = 16; mask <= 32; mask <<= 1) {
        u32 P[LK];
#pragma unroll
        for (int m = 0; m < LK; ++m) P[m] = (u32)__shfl_xor((int)L[m], mask);
        mergeKeep<LK, LK, LK, u32>(L, P);
    }

    if (lane < 16) {
        int row = r0 + l15;
        if (row < N) {
            u32* dst = wsK + ((size_t)row * NSPLIT + split) * LK;
#pragma unroll
            for (int m = 0; m < LK; ++m) dst[m] = L[m];
        }
    }
}

// ---------------------------------------------------------------------------
// 4 lanes per row. Each lane merges 4 split-lists (u32); 2 shfl_xor
// butterflies give the global bf16-top-12. Each lane rescores 3 candidates in
// exact fp32; final top-5 via exact packed-u64 butterfly (== reference
// tie-break). Lane 0 of each row does the symmetric atomic scatter.
// ---------------------------------------------------------------------------
__global__ __launch_bounds__(256) void rescore_scatter(
    const u32* __restrict__ wsK, const float* __restrict__ x, const float* __restrict__ xxf,
    float* __restrict__ out, int N)
{
    const int lane = threadIdx.x & 63;
    const int wave = threadIdx.x >> 6;
    const int sub  = lane & 3;
    const int row  = blockIdx.x * 64 + wave * 16 + (lane >> 2);
    const bool vrow = (row < N);
    const int rr = vrow ? row : 0;

    // merge my 4 lists, then butterfly to global top-12
    u32 cur[GK];
    {
        const u32* Lp = wsK + ((size_t)rr * NSPLIT + 4 * sub) * LK;
#pragma unroll
        for (int m = 0; m < LK; ++m) cur[m] = Lp[m];
#pragma unroll
        for (int m = LK; m < GK; ++m) cur[m] = 0u;
#pragma unroll
        for (int l = 1; l < 4; ++l) {
            u32 b[LK];
#pragma unroll
            for (int m = 0; m < LK; ++m) b[m] = Lp[l * LK + m];
            mergeKeep<GK, GK, LK, u32>(cur, b);
        }
    }
#pragma unroll
    for (int mask = 1; mask <= 2; mask <<= 1) {
        u32 P[GK];
#pragma unroll
        for (int m = 0; m < GK; ++m) P[m] = (u32)__shfl_xor((int)cur[m], mask);
        mergeKeep<GK, GK, GK, u32>(cur, P);
    }

    // exact fp32 rescore of my 3 candidates
    const float nxi = xxf[rr];
    int   cj[3]; bool cval[3];
    float d[3] = {0.f, 0.f, 0.f};
    const f32x4v* pj[3];
#pragma unroll
    for (int c = 0; c < 3; ++c) {
        int j = idx32(cur[sub * 3 + c]);
        cval[c] = (j < N) && (cur[sub * 3 + c] != 0u);
        cj[c] = cval[c] ? j : 0;
        pj[c] = (const f32x4v*)(x + (size_t)cj[c] * D);
    }
    const f32x4v* xip = (const f32x4v*)(x + (size_t)rr * D);
#pragma unroll
    for (int t = 0; t < 16; ++t) {
        const f32x4v xv = xip[t];
#pragma unroll
        for (int c = 0; c < 3; ++c) {
            const f32x4v pv = pj[c][t];
            d[c] = fmaf(xv[0], pv[0], d[c]);
            d[c] = fmaf(xv[1], pv[1], d[c]);
            d[c] = fmaf(xv[2], pv[2], d[c]);
            d[c] = fmaf(xv[3], pv[3], d[c]);
        }
    }
    u64 F[K];
#pragma unroll
    for (int c = 0; c < 3; ++c) {
        float val = 2.f * d[c] - nxi - xxf[cj[c]];
        F[c] = cval[c] ? packKV(val, cj[c]) : 0ull;
    }
    F[3] = 0ull; F[4] = 0ull;
    // sort first 3 desc
    { u64 a0=F[0],a1=F[1],a2=F[2];
      if (a0 < a1) { u64 t0=a0; a0=a1; a1=t0; }
      if (a1 < a2) { u64 t0=a1; a1=a2; a2=t0; }
      if (a0 < a1) { u64 t0=a0; a0=a1; a1=t0; }
      F[0]=a0; F[1]=a1; F[2]=a2; }
#pragma unroll
    for (int mask = 1; mask <= 2; mask <<= 1) {
        u64 P[K];
#pragma unroll
        for (int m = 0; m < K; ++m) P[m] = __shfl_xor(F[m], mask);
        mergeKeep<K, K, K, u64>(F, P);
    }

    if (sub == 0 && vrow) {
#pragma unroll
        for (int m = 0; m < K; ++m) {
            int j = (int)(~(u32)F[m]);
            if ((unsigned)j < (unsigned)N && j != row) {
                float v = unpackV(F[m]);
                atomicAdd(out + (size_t)row * N + j, v);
                atomicAdd(out + (size_t)j * N + row, v);
            }
        }
    }
}

// ---------------------------------------------------------------------------
extern "C" void kernel_launch(void* const* d_in, const int* in_sizes, int n_in,
                              void* d_out, int out_size, void* d_ws, size_t ws_size,
                              hipStream_t stream) {
    const float* x = (const float*)d_in[0];
    const int N = in_sizes[0] / D;          // 10000
    float* out = (float*)d_out;

    // Workspace layout (fixed offsets, padded for the 2-deep prefetch
    // overrun: reads <=32 tiles = 64 KB past xbA, <=2 KB past xxf):
    //   xbA @ 0x000000: 625*128*16B = 1.28 MB (+64 KB pad)  -> ends < 0x150000
    //   xxf @ 0x150000: 40 KB (+pad)                        -> ends < 0x160000
    //   wsK @ 0x160000: N*NSPLIT*LK u32 = 5.12 MB
    const size_t oXB = 0;
    const size_t oXX = 0x150000;
    const size_t oWK = 0x160000;
    __bf16* xbA = (__bf16*)((char*)d_ws + oXB);
    float*  xxf = (float*)((char*)d_ws + oXX);
    u32*    wsK = (u32*)((char*)d_ws + oWK);

    const int prepThreads = NTILES * 2 * 64 + N;         // 90000
    prep<<<(prepThreads + 255) / 256, 256, 0, stream>>>(x, xbA, xxf, N);

    long long totalF4 = (long long)out_size / 4;         // 25e6
    const int nBlocksTotal = 3024;                       // 504 zero + 2520 compute slots
    const int nZero = (nBlocksTotal + 5) / 6;            // 504
    int f4PerZ = (int)((totalF4 + nZero - 1) / nZero);   // ~49604
    topk_zero_mfma<<<nBlocksTotal, 256, 0, stream>>>(
        xbA, xxf, N, wsK, out, totalF4, nZero, f4PerZ);

    rescore_scatter<<<ROWBLK, 256, 0, stream>>>(wsK, x, xxf, out, N);
}

// Round 4
// 451.195 us; speedup vs baseline: 1.2597x; 1.0028x over previous
//
#include <hip/hip_runtime.h>

#define D 64
#define K 5
#define LK 8                  // per-lane / per-split candidate list length
#define GK 12                 // global candidates rescored per row
#define NSPLIT 16
#define NTILES 625            // 10000 / 16 exactly
#define ROWBLK 157            // ceil(10000/64)
#define NCOMP (ROWBLK * NSPLIT)   // 2512 compute blocks
typedef unsigned int u32;
typedef unsigned long long u64;
typedef __bf16 bf16x8 __attribute__((ext_vector_type(8)));
typedef float  f32x4v __attribute__((ext_vector_type(4)));

// v_med3_u32 (GCN3+; no HIP builtin)
__device__ __forceinline__ u32 med3u(u32 a, u32 b, u32 c) {
    u32 r;
    asm("v_med3_u32 %0, %1, %2, %3" : "=v"(r) : "v"(a), "v"(b), "v"(c));
    return r;
}

// ---- u32 key: [31:14] = top bits of FULL monotone fp32 map, [13:0] = ~idx.
// bigger key == (bigger value, then lower idx). ----
__device__ __forceinline__ u32 pack32(float v, int idx) {
    u32 u = __float_as_uint(v);
    u ^= ((u32)((int)u >> 31)) | 0x80000000u;
    return (u & 0xFFFFC000u) | ((~(u32)idx) & 0x3FFFu);
}
__device__ __forceinline__ int idx32(u32 key) { return (int)((~key) & 0x3FFFu); }

// exact final key (value, then lower idx)
__device__ __forceinline__ u64 packKV(float v, int idx) {
    u32 u = __float_as_uint(v);
    u ^= ((u32)((int)u >> 31)) | 0x80000000u;
    return ((u64)u << 32) | (u32)(~idx);
}
__device__ __forceinline__ float unpackV(u64 key) {
    u32 hu = (u32)(key >> 32);
    return (hu & 0x80000000u) ? __uint_as_float(hu & 0x7fffffffu)
                              : __uint_as_float(~hu);
}

// branchless merge of two sorted-desc lists, keep first LO into a[]
template<int LO, int LA, int LB, typename T>
__device__ __forceinline__ void mergeKeep(T a[LA], const T b[LB]) {
    T A[LA], B[LB], out[LO];
#pragma unroll
    for (int i = 0; i < LA; ++i) A[i] = a[i];
#pragma unroll
    for (int i = 0; i < LB; ++i) B[i] = b[i];
#pragma unroll
    for (int m = 0; m < LO; ++m) {
        bool ta = A[0] >= B[0];
        out[m] = ta ? A[0] : B[0];
#pragma unroll
        for (int i = 0; i < LA - 1; ++i) A[i] = ta ? A[i + 1] : A[i];
        A[LA - 1] = ta ? (T)0 : A[LA - 1];
#pragma unroll
        for (int i = 0; i < LB - 1; ++i) B[i] = ta ? B[i] : B[i + 1];
        B[LB - 1] = ta ? B[LB - 1] : (T)0;
    }
#pragma unroll
    for (int m = 0; m < LO; ++m) a[m] = out[m];
}

// ---------------------------------------------------------------------------
// Prep: repack x into MFMA-fragment order + row norms.
// xbA[tile][khalf][lane][8 bf16]: lane = q*16+r holds x[tile*16+r][kh*32+q*8..+8).
// ---------------------------------------------------------------------------
__global__ __launch_bounds__(256) void prep(
    const float* __restrict__ x, __bf16* __restrict__ xbA, float* __restrict__ xxf, int N)
{
    int g = blockIdx.x * 256 + threadIdx.x;
    const int REPACK = NTILES * 2 * 64;          // 80000
    if (g < REPACK) {
        int tile = g >> 7;
        int rem  = g & 127;
        int kh   = rem >> 6;
        int lane = rem & 63;
        int q = lane >> 4, r = lane & 15;
        int row = tile * 16 + r;
        int k0  = kh * 32 + q * 8;
        const float4* p = (const float4*)(x + (size_t)row * D + k0);
        float4 v0 = p[0], v1 = p[1];
        bf16x8 o;
        o[0] = (__bf16)v0.x; o[1] = (__bf16)v0.y; o[2] = (__bf16)v0.z; o[3] = (__bf16)v0.w;
        o[4] = (__bf16)v1.x; o[5] = (__bf16)v1.y; o[6] = (__bf16)v1.z; o[7] = (__bf16)v1.w;
        ((bf16x8*)xbA)[g] = o;
        return;
    }
    int i = g - REPACK;
    if (i >= N) return;
    const float4* p = (const float4*)(x + (size_t)i * D);
    float s = 0.f;
#pragma unroll
    for (int t = 0; t < 16; ++t) {
        float4 v = p[t];
        s += v.x * v.x + v.y * v.y + v.z * v.z + v.w * v.w;
    }
    xxf[i] = s;
}

// ---------------------------------------------------------------------------
// Block-specialized zero/compute split, XCD-FIXED:
// Zero blocks are chosen in GROUPS OF 8 CONSECUTIVE blocks ((bx>>3)%6==0).
// Rationale: block->XCD assignment round-robins as bx%8; the old bx%6
// selector aliased to even XCDs only (lcm(6,8)=24 -> residues {0,2,4,6}),
// halving write fabric BW (~3 TB/s -> 400 MB zero = ~150 us, the kernel's
// critical path). Groups of 8 cover one full XCD round -> all 8 XCDs write.
// Zero:compute ratio per CU unchanged (1:5, 504 zero / 2520 compute slots).
// Compute path identical to r3 (2-deep prefetch, split accumulators).
// ---------------------------------------------------------------------------
__global__ __launch_bounds__(256, 6) void topk_zero_mfma(
    const __bf16* __restrict__ xbA, const float* __restrict__ xxf, int N,
    u32* __restrict__ wsK, float* __restrict__ outZ, long long totalF4,
    int nZero, int f4PerZ)
{
    const int bx  = blockIdx.x;
    const int tid = threadIdx.x;
    const int g8  = bx >> 3;                     // group of 8 consecutive blocks
    const int r8  = bx & 7;

    if (g8 % 6 == 0) {
        // ---------------- zero block (XCD-spread) ----------------
        int zid = (g8 / 6) * 8 + r8;
        if (zid >= nZero) return;
        long long s = (long long)zid * f4PerZ;
        long long e = s + f4PerZ; if (e > totalF4) e = totalF4;
        const f32x4v z = {0.f, 0.f, 0.f, 0.f};
        for (long long i = s + tid; i < e; i += 256)
            __builtin_nontemporal_store(z, (f32x4v*)(outZ + 4 * i));
        return;
    }

    // ---------------- compute block ----------------
    const int cid = bx - (g8 / 6 + 1) * 8;       // dense index over non-zero blocks
    if (cid >= NCOMP) return;
    const int split = cid / ROWBLK;              // 0..15
    const int rb    = cid - split * ROWBLK;      // 0..156

    const int lane = tid & 63;
    const int wave = tid >> 6;
    const int l15  = lane & 15;
    const int q    = lane >> 4;                  // col quad
    const int r0 = rb * 64 + wave * 16;

    const bf16x8* fb = (const bf16x8*)xbA;       // fragment base, 128 per tile

    // B fragments: my 16-row tile (clamped for tail waves), held in regs
    int bt = r0 >> 4; if (bt > NTILES - 1) bt = NTILES - 1;
    const bf16x8 B0 = fb[bt * 128 + lane];
    const bf16x8 B1 = fb[bt * 128 + 64 + lane];

    // pointer-bumped loop state
    const bf16x8* ap = fb + (size_t)split * 128 + lane;
    const float* xcp = xxf + split * 16 + q * 4;
    int cbase = split * 16 + q * 4;
    const int apBump = NSPLIT * 128;             // 2048 fragments
    const int xcBump = NSPLIT * 16;              // 256 floats

    u32 L[LK];
#pragma unroll
    for (int m = 0; m < LK; ++m) L[m] = 0u;      // 0 < any real packed key

    // 2-deep software pipeline: prefetch reads run <=32 tiles past the
    // table; workspace layout pads for it (64 KB after xbA, 24 KB after xxf).
    bf16x8 A0a = ap[0];
    bf16x8 A1a = ap[64];
    f32x4v xca = *(const f32x4v*)xcp;
    ap += apBump; xcp += xcBump;
    bf16x8 A0b = ap[0];
    bf16x8 A1b = ap[64];
    f32x4v xcb = *(const f32x4v*)xcp;

    for (int t = split; t < NTILES; t += NSPLIT) {
        ap += apBump; xcp += xcBump;
        const bf16x8 nA0 = ap[0];
        const bf16x8 nA1 = ap[64];
        const f32x4v nxc = *(const f32x4v*)xcp;

        f32x4v acc0 = {0.f, 0.f, 0.f, 0.f};
        f32x4v acc1 = {0.f, 0.f, 0.f, 0.f};
        acc0 = __builtin_amdgcn_mfma_f32_16x16x32_bf16(A0a, B0, acc0, 0, 0, 0);
        acc1 = __builtin_amdgcn_mfma_f32_16x16x32_bf16(A1a, B1, acc1, 0, 0, 0);

        // full monotone key map + med3 insertion
#pragma unroll
        for (int v = 0; v < 4; ++v) {
            float dk = fmaf(-0.5f, xca[v], acc0[v] + acc1[v]);  // ordering == distance ordering
            u32 key = pack32(dk, cbase + v);
            u32 n0 = max(L[0], key);
            u32 n1 = med3u(L[0], L[1], key);
            u32 n2 = med3u(L[1], L[2], key);
            u32 n3 = med3u(L[2], L[3], key);
            u32 n4 = med3u(L[3], L[4], key);
            u32 n5 = med3u(L[4], L[5], key);
            u32 n6 = med3u(L[5], L[6], key);
            u32 n7 = med3u(L[6], L[7], key);
            L[0]=n0; L[1]=n1; L[2]=n2; L[3]=n3; L[4]=n4; L[5]=n5; L[6]=n6; L[7]=n7;
        }
        cbase += xcBump;
        A0a = A0b; A1a = A1b; xca = xcb;
        A0b = nA0; A1b = nA1; xcb = nxc;
    }

    // butterfly merge across the 4 quads sharing a row
#pragma unroll
    for (int mask = 16; mask <= 32; mask <<= 1) {
        u32 P[LK];
#pragma unroll
        for (int m = 0; m < LK; ++m) P[m] = (u32)__shfl_xor((int)L[m], mask);
        mergeKeep<LK, LK, LK, u32>(L, P);
    }

    if (lane < 16) {
        int row = r0 + l15;
        if (row < N) {
            u32* dst = wsK + ((size_t)row * NSPLIT + split) * LK;
#pragma unroll
            for (int m = 0; m < LK; ++m) dst[m] = L[m];
        }
    }
}

// ---------------------------------------------------------------------------
// 4 lanes per row. Each lane merges 4 split-lists (u32); 2 shfl_xor
// butterflies give the global bf16-top-12. Each lane rescores 3 candidates in
// exact fp32; final top-5 via exact packed-u64 butterfly (== reference
// tie-break). Lane 0 of each row does the symmetric atomic scatter.
// ---------------------------------------------------------------------------
__global__ __launch_bounds__(256) void rescore_scatter(
    const u32* __restrict__ wsK, const float* __restrict__ x, const float* __restrict__ xxf,
    float* __restrict__ out, int N)
{
    const int lane = threadIdx.x & 63;
    const int wave = threadIdx.x >> 6;
    const int sub  = lane & 3;
    const int row  = blockIdx.x * 64 + wave * 16 + (lane >> 2);
    const bool vrow = (row < N);
    const int rr = vrow ? row : 0;

    // merge my 4 lists, then butterfly to global top-12
    u32 cur[GK];
    {
        const u32* Lp = wsK + ((size_t)rr * NSPLIT + 4 * sub) * LK;
#pragma unroll
        for (int m = 0; m < LK; ++m) cur[m] = Lp[m];
#pragma unroll
        for (int m = LK; m < GK; ++m) cur[m] = 0u;
#pragma unroll
        for (int l = 1; l < 4; ++l) {
            u32 b[LK];
#pragma unroll
            for (int m = 0; m < LK; ++m) b[m] = Lp[l * LK + m];
            mergeKeep<GK, GK, LK, u32>(cur, b);
        }
    }
#pragma unroll
    for (int mask = 1; mask <= 2; mask <<= 1) {
        u32 P[GK];
#pragma unroll
        for (int m = 0; m < GK; ++m) P[m] = (u32)__shfl_xor((int)cur[m], mask);
        mergeKeep<GK, GK, GK, u32>(cur, P);
    }

    // exact fp32 rescore of my 3 candidates
    const float nxi = xxf[rr];
    int   cj[3]; bool cval[3];
    float d[3] = {0.f, 0.f, 0.f};
    const f32x4v* pj[3];
#pragma unroll
    for (int c = 0; c < 3; ++c) {
        int j = idx32(cur[sub * 3 + c]);
        cval[c] = (j < N) && (cur[sub * 3 + c] != 0u);
        cj[c] = cval[c] ? j : 0;
        pj[c] = (const f32x4v*)(x + (size_t)cj[c] * D);
    }
    const f32x4v* xip = (const f32x4v*)(x + (size_t)rr * D);
#pragma unroll
    for (int t = 0; t < 16; ++t) {
        const f32x4v xv = xip[t];
#pragma unroll
        for (int c = 0; c < 3; ++c) {
            const f32x4v pv = pj[c][t];
            d[c] = fmaf(xv[0], pv[0], d[c]);
            d[c] = fmaf(xv[1], pv[1], d[c]);
            d[c] = fmaf(xv[2], pv[2], d[c]);
            d[c] = fmaf(xv[3], pv[3], d[c]);
        }
    }
    u64 F[K];
#pragma unroll
    for (int c = 0; c < 3; ++c) {
        float val = 2.f * d[c] - nxi - xxf[cj[c]];
        F[c] = cval[c] ? packKV(val, cj[c]) : 0ull;
    }
    F[3] = 0ull; F[4] = 0ull;
    // sort first 3 desc
    { u64 a0=F[0],a1=F[1],a2=F[2];
      if (a0 < a1) { u64 t0=a0; a0=a1; a1=t0; }
      if (a1 < a2) { u64 t0=a1; a1=a2; a2=t0; }
      if (a0 < a1) { u64 t0=a0; a0=a1; a1=t0; }
      F[0]=a0; F[1]=a1; F[2]=a2; }
#pragma unroll
    for (int mask = 1; mask <= 2; mask <<= 1) {
        u64 P[K];
#pragma unroll
        for (int m = 0; m < K; ++m) P[m] = __shfl_xor(F[m], mask);
        mergeKeep<K, K, K, u64>(F, P);
    }

    if (sub == 0 && vrow) {
#pragma unroll
        for (int m = 0; m < K; ++m) {
            int j = (int)(~(u32)F[m]);
            if ((unsigned)j < (unsigned)N && j != row) {
                float v = unpackV(F[m]);
                atomicAdd(out + (size_t)row * N + j, v);
                atomicAdd(out + (size_t)j * N + row, v);
            }
        }
    }
}

// ---------------------------------------------------------------------------
extern "C" void kernel_launch(void* const* d_in, const int* in_sizes, int n_in,
                              void* d_out, int out_size, void* d_ws, size_t ws_size,
                              hipStream_t stream) {
    const float* x = (const float*)d_in[0];
    const int N = in_sizes[0] / D;          // 10000
    float* out = (float*)d_out;

    // Workspace layout (fixed offsets, padded for the 2-deep prefetch
    // overrun: reads <=32 tiles = 64 KB past xbA, <=2 KB past xxf):
    //   xbA @ 0x000000: 625*128*16B = 1.28 MB (+64 KB pad)  -> ends < 0x150000
    //   xxf @ 0x150000: 40 KB (+pad)                        -> ends < 0x160000
    //   wsK @ 0x160000: N*NSPLIT*LK u32 = 5.12 MB
    const size_t oXB = 0;
    const size_t oXX = 0x150000;
    const size_t oWK = 0x160000;
    __bf16* xbA = (__bf16*)((char*)d_ws + oXB);
    float*  xxf = (float*)((char*)d_ws + oXX);
    u32*    wsK = (u32*)((char*)d_ws + oWK);

    const int prepThreads = NTILES * 2 * 64 + N;         // 90000
    prep<<<(prepThreads + 255) / 256, 256, 0, stream>>>(x, xbA, xxf, N);

    long long totalF4 = (long long)out_size / 4;         // 25e6
    // 63 supergroups of 48 blocks = 3024 total: 504 zero (8-consecutive
    // bursts -> all XCDs) + 2520 compute slots (>= NCOMP=2512).
    const int nBlocksTotal = 3024;
    const int nZero = 504;
    int f4PerZ = (int)((totalF4 + nZero - 1) / nZero);   // ~49604
    topk_zero_mfma<<<nBlocksTotal, 256, 0, stream>>>(
        xbA, xxf, N, wsK, out, totalF4, nZero, f4PerZ);

    rescore_scatter<<<ROWBLK, 256, 0, stream>>>(wsK, x, xxf, out, N);
}

// Round 5
// 445.223 us; speedup vs baseline: 1.2766x; 1.0134x over previous
//
#include <hip/hip_runtime.h>

#define D 64
#define K 5
#define LK 8                  // per-lane / per-split candidate list length
#define GK 12                 // global candidates rescored per row
#define NSPLIT 16
#define NTILES 625            // 10000 / 16 exactly
#define ROWBLK 157            // ceil(10000/64)
#define NCOMP (ROWBLK * NSPLIT)   // 2512 compute blocks
typedef unsigned int u32;
typedef unsigned long long u64;
typedef __bf16 bf16x8 __attribute__((ext_vector_type(8)));
typedef float  f32x4v __attribute__((ext_vector_type(4)));

// v_med3_u32 (GCN3+; no HIP builtin)
__device__ __forceinline__ u32 med3u(u32 a, u32 b, u32 c) {
    u32 r;
    asm("v_med3_u32 %0, %1, %2, %3" : "=v"(r) : "v"(a), "v"(b), "v"(c));
    return r;
}

// ---- u32 key: [31:14] = top bits of FULL monotone fp32 map, [13:0] = 0x3FFF-idx
// (== (~idx)&0x3FFF for idx<16384). bigger key == (bigger value, then lower idx).
__device__ __forceinline__ u32 pack32(float v, int idx) {
    u32 u = __float_as_uint(v);
    u ^= ((u32)((int)u >> 31)) | 0x80000000u;
    return (u & 0xFFFFC000u) | ((~(u32)idx) & 0x3FFFu);
}
__device__ __forceinline__ int idx32(u32 key) { return (int)((~key) & 0x3FFFu); }

// exact final key (value, then lower idx)
__device__ __forceinline__ u64 packKV(float v, int idx) {
    u32 u = __float_as_uint(v);
    u ^= ((u32)((int)u >> 31)) | 0x80000000u;
    return ((u64)u << 32) | (u32)(~idx);
}
__device__ __forceinline__ float unpackV(u64 key) {
    u32 hu = (u32)(key >> 32);
    return (hu & 0x80000000u) ? __uint_as_float(hu & 0x7fffffffu)
                              : __uint_as_float(~hu);
}

// branchless merge of two sorted-desc lists, keep first LO into a[]
template<int LO, int LA, int LB, typename T>
__device__ __forceinline__ void mergeKeep(T a[LA], const T b[LB]) {
    T A[LA], B[LB], out[LO];
#pragma unroll
    for (int i = 0; i < LA; ++i) A[i] = a[i];
#pragma unroll
    for (int i = 0; i < LB; ++i) B[i] = b[i];
#pragma unroll
    for (int m = 0; m < LO; ++m) {
        bool ta = A[0] >= B[0];
        out[m] = ta ? A[0] : B[0];
#pragma unroll
        for (int i = 0; i < LA - 1; ++i) A[i] = ta ? A[i + 1] : A[i];
        A[LA - 1] = ta ? (T)0 : A[LA - 1];
#pragma unroll
        for (int i = 0; i < LB - 1; ++i) B[i] = ta ? B[i] : B[i + 1];
        B[LB - 1] = ta ? B[LB - 1] : (T)0;
    }
#pragma unroll
    for (int m = 0; m < LO; ++m) a[m] = out[m];
}

// ---------------------------------------------------------------------------
// Prep: repack x into MFMA-fragment order + row norms (raw and -0.5x for the
// MFMA C-operand fold).
// xbA[tile][khalf][lane][8 bf16]: lane = q*16+r holds x[tile*16+r][kh*32+q*8..+8).
// ---------------------------------------------------------------------------
__global__ __launch_bounds__(256) void prep(
    const float* __restrict__ x, __bf16* __restrict__ xbA,
    float* __restrict__ xxf, float* __restrict__ xxh, int N)
{
    int g = blockIdx.x * 256 + threadIdx.x;
    const int REPACK = NTILES * 2 * 64;          // 80000
    if (g < REPACK) {
        int tile = g >> 7;
        int rem  = g & 127;
        int kh   = rem >> 6;
        int lane = rem & 63;
        int q = lane >> 4, r = lane & 15;
        int row = tile * 16 + r;
        int k0  = kh * 32 + q * 8;
        const float4* p = (const float4*)(x + (size_t)row * D + k0);
        float4 v0 = p[0], v1 = p[1];
        bf16x8 o;
        o[0] = (__bf16)v0.x; o[1] = (__bf16)v0.y; o[2] = (__bf16)v0.z; o[3] = (__bf16)v0.w;
        o[4] = (__bf16)v1.x; o[5] = (__bf16)v1.y; o[6] = (__bf16)v1.z; o[7] = (__bf16)v1.w;
        ((bf16x8*)xbA)[g] = o;
        return;
    }
    int i = g - REPACK;
    if (i >= N) return;
    const float4* p = (const float4*)(x + (size_t)i * D);
    float s = 0.f;
#pragma unroll
    for (int t = 0; t < 16; ++t) {
        float4 v = p[t];
        s += v.x * v.x + v.y * v.y + v.z * v.z + v.w * v.w;
    }
    xxf[i] = s;
    xxh[i] = -0.5f * s;
}

// ---------------------------------------------------------------------------
// Block-specialized zero/compute split (r4 skeleton). Round-5 changes:
//  * zero leg uses PLAIN dwordx4 stores (harness fill achieves 6.1 TB/s with
//    plain; NT measured ~4 TB/s and shares the VMEM queue dynamics with
//    compute loads) — tests H1 (NT throughput cap) + H3 (pipe coupling).
//  * compute inner loop slimmed ~35% (H2): -0.5*||xj||^2 folded into the
//    MFMA C-operand (xxh precomputed in prep); candidate-index pack uses
//    base16k = 0x3FFF - cbase maintained by one sub/iter, so per-candidate
//    key assembly is ashr+or+xor+sub+and_or instead of ~10 ops.
//  * natural occupancy (no min-waves bound -> no silent spill risk).
// ---------------------------------------------------------------------------
__global__ __launch_bounds__(256) void topk_zero_mfma(
    const __bf16* __restrict__ xbA, const float* __restrict__ xxh, int N,
    u32* __restrict__ wsK, float* __restrict__ outZ, long long totalF4,
    int nZero, int f4PerZ)
{
    const int bx  = blockIdx.x;
    const int tid = threadIdx.x;
    const int g8  = bx >> 3;                     // group of 8 consecutive blocks
    const int r8  = bx & 7;

    if (g8 % 6 == 0) {
        // ---------------- zero block (plain streaming stores) ----------------
        int zid = (g8 / 6) * 8 + r8;
        if (zid >= nZero) return;
        long long s = (long long)zid * f4PerZ;
        long long e = s + f4PerZ; if (e > totalF4) e = totalF4;
        const f32x4v z = {0.f, 0.f, 0.f, 0.f};
        for (long long i = s + tid; i < e; i += 256)
            *(f32x4v*)(outZ + 4 * i) = z;
        return;
    }

    // ---------------- compute block ----------------
    const int cid = bx - (g8 / 6 + 1) * 8;       // dense index over non-zero blocks
    if (cid >= NCOMP) return;
    const int split = cid / ROWBLK;              // 0..15
    const int rb    = cid - split * ROWBLK;      // 0..156

    const int lane = tid & 63;
    const int wave = tid >> 6;
    const int l15  = lane & 15;
    const int q    = lane >> 4;                  // col quad
    const int r0 = rb * 64 + wave * 16;

    const bf16x8* fb = (const bf16x8*)xbA;       // fragment base, 128 per tile

    // B fragments: my 16-row tile (clamped for tail waves), held in regs
    int bt = r0 >> 4; if (bt > NTILES - 1) bt = NTILES - 1;
    const bf16x8 B0 = fb[bt * 128 + lane];
    const bf16x8 B1 = fb[bt * 128 + 64 + lane];

    // pointer-bumped loop state
    const bf16x8* ap = fb + (size_t)split * 128 + lane;
    const float* xhp = xxh + split * 16 + q * 4;
    u32 base16k = 0x3FFFu - (u32)(split * 16 + q * 4);   // 0x3FFF - cbase
    const int apBump = NSPLIT * 128;             // 2048 fragments
    const int xcBump = NSPLIT * 16;              // 256 floats

    u32 L[LK];
#pragma unroll
    for (int m = 0; m < LK; ++m) L[m] = 0u;      // 0 < any real packed key

    // 1-deep software pipeline (latency proven non-binding in r3).
    // Prefetch overruns read <=16 tiles (32 KB) past xbA and ~1 KB past xxh;
    // workspace pads cover both.
    bf16x8 A0 = ap[0];
    bf16x8 A1 = ap[64];
    f32x4v xh = *(const f32x4v*)xhp;

    for (int t = split; t < NTILES; t += NSPLIT) {
        ap += apBump; xhp += xcBump;
        const bf16x8 nA0 = ap[0];
        const bf16x8 nA1 = ap[64];
        const f32x4v nxh = *(const f32x4v*)xhp;

        f32x4v acc = xh;                          // C init = -0.5*||xj||^2
        acc = __builtin_amdgcn_mfma_f32_16x16x32_bf16(A0, B0, acc, 0, 0, 0);
        acc = __builtin_amdgcn_mfma_f32_16x16x32_bf16(A1, B1, acc, 0, 0, 0);

        // monotone key map (5 ops) + med3 insertion (8 ops) per candidate
#pragma unroll
        for (int v = 0; v < 4; ++v) {
            u32 u = __float_as_uint(acc[v]);
            u ^= ((u32)((int)u >> 31)) | 0x80000000u;
            u32 key = (u & 0xFFFFC000u) | (base16k - (u32)v);
            u32 n0 = max(L[0], key);
            u32 n1 = med3u(L[0], L[1], key);
            u32 n2 = med3u(L[1], L[2], key);
            u32 n3 = med3u(L[2], L[3], key);
            u32 n4 = med3u(L[3], L[4], key);
            u32 n5 = med3u(L[4], L[5], key);
            u32 n6 = med3u(L[5], L[6], key);
            u32 n7 = med3u(L[6], L[7], key);
            L[0]=n0; L[1]=n1; L[2]=n2; L[3]=n3; L[4]=n4; L[5]=n5; L[6]=n6; L[7]=n7;
        }
        base16k -= (u32)xcBump;
        A0 = nA0; A1 = nA1; xh = nxh;
    }

    // butterfly merge across the 4 quads sharing a row
#pragma unroll
    for (int mask = 16; mask <= 32; mask <<= 1) {
        u32 P[LK];
#pragma unroll
        for (int m = 0; m < LK; ++m) P[m] = (u32)__shfl_xor((int)L[m], mask);
        mergeKeep<LK, LK, LK, u32>(L, P);
    }

    if (lane < 16) {
        int row = r0 + l15;
        if (row < N) {
            u32* dst = wsK + ((size_t)row * NSPLIT + split) * LK;
#pragma unroll
            for (int m = 0; m < LK; ++m) dst[m] = L[m];
        }
    }
}

// ---------------------------------------------------------------------------
// 4 lanes per row. Each lane merges 4 split-lists (u32); 2 shfl_xor
// butterflies give the global bf16-top-12. Each lane rescores 3 candidates in
// exact fp32; final top-5 via exact packed-u64 butterfly (== reference
// tie-break). Lane 0 of each row does the symmetric atomic scatter.
// ---------------------------------------------------------------------------
__global__ __launch_bounds__(256) void rescore_scatter(
    const u32* __restrict__ wsK, const float* __restrict__ x, const float* __restrict__ xxf,
    float* __restrict__ out, int N)
{
    const int lane = threadIdx.x & 63;
    const int wave = threadIdx.x >> 6;
    const int sub  = lane & 3;
    const int row  = blockIdx.x * 64 + wave * 16 + (lane >> 2);
    const bool vrow = (row < N);
    const int rr = vrow ? row : 0;

    // merge my 4 lists, then butterfly to global top-12
    u32 cur[GK];
    {
        const u32* Lp = wsK + ((size_t)rr * NSPLIT + 4 * sub) * LK;
#pragma unroll
        for (int m = 0; m < LK; ++m) cur[m] = Lp[m];
#pragma unroll
        for (int m = LK; m < GK; ++m) cur[m] = 0u;
#pragma unroll
        for (int l = 1; l < 4; ++l) {
            u32 b[LK];
#pragma unroll
            for (int m = 0; m < LK; ++m) b[m] = Lp[l * LK + m];
            mergeKeep<GK, GK, LK, u32>(cur, b);
        }
    }
#pragma unroll
    for (int mask = 1; mask <= 2; mask <<= 1) {
        u32 P[GK];
#pragma unroll
        for (int m = 0; m < GK; ++m) P[m] = (u32)__shfl_xor((int)cur[m], mask);
        mergeKeep<GK, GK, GK, u32>(cur, P);
    }

    // exact fp32 rescore of my 3 candidates
    const float nxi = xxf[rr];
    int   cj[3]; bool cval[3];
    float d[3] = {0.f, 0.f, 0.f};
    const f32x4v* pj[3];
#pragma unroll
    for (int c = 0; c < 3; ++c) {
        int j = idx32(cur[sub * 3 + c]);
        cval[c] = (j < N) && (cur[sub * 3 + c] != 0u);
        cj[c] = cval[c] ? j : 0;
        pj[c] = (const f32x4v*)(x + (size_t)cj[c] * D);
    }
    const f32x4v* xip = (const f32x4v*)(x + (size_t)rr * D);
#pragma unroll
    for (int t = 0; t < 16; ++t) {
        const f32x4v xv = xip[t];
#pragma unroll
        for (int c = 0; c < 3; ++c) {
            const f32x4v pv = pj[c][t];
            d[c] = fmaf(xv[0], pv[0], d[c]);
            d[c] = fmaf(xv[1], pv[1], d[c]);
            d[c] = fmaf(xv[2], pv[2], d[c]);
            d[c] = fmaf(xv[3], pv[3], d[c]);
        }
    }
    u64 F[K];
#pragma unroll
    for (int c = 0; c < 3; ++c) {
        float val = 2.f * d[c] - nxi - xxf[cj[c]];
        F[c] = cval[c] ? packKV(val, cj[c]) : 0ull;
    }
    F[3] = 0ull; F[4] = 0ull;
    // sort first 3 desc
    { u64 a0=F[0],a1=F[1],a2=F[2];
      if (a0 < a1) { u64 t0=a0; a0=a1; a1=t0; }
      if (a1 < a2) { u64 t0=a1; a1=a2; a2=t0; }
      if (a0 < a1) { u64 t0=a0; a0=a1; a1=t0; }
      F[0]=a0; F[1]=a1; F[2]=a2; }
#pragma unroll
    for (int mask = 1; mask <= 2; mask <<= 1) {
        u64 P[K];
#pragma unroll
        for (int m = 0; m < K; ++m) P[m] = __shfl_xor(F[m], mask);
        mergeKeep<K, K, K, u64>(F, P);
    }

    if (sub == 0 && vrow) {
#pragma unroll
        for (int m = 0; m < K; ++m) {
            int j = (int)(~(u32)F[m]);
            if ((unsigned)j < (unsigned)N && j != row) {
                float v = unpackV(F[m]);
                atomicAdd(out + (size_t)row * N + j, v);
                atomicAdd(out + (size_t)j * N + row, v);
            }
        }
    }
}

// ---------------------------------------------------------------------------
extern "C" void kernel_launch(void* const* d_in, const int* in_sizes, int n_in,
                              void* d_out, int out_size, void* d_ws, size_t ws_size,
                              hipStream_t stream) {
    const float* x = (const float*)d_in[0];
    const int N = in_sizes[0] / D;          // 10000
    float* out = (float*)d_out;

    // Workspace layout (fixed offsets; pads cover the 1-deep prefetch
    // overrun: <=16 tiles = 32 KB past xbA, ~1 KB past xxh):
    //   xbA @ 0x000000: 625*128*16B = 1.28 MB (+pad)  -> ends < 0x150000
    //   xxf @ 0x150000: 40 KB raw norms
    //   xxh @ 0x160000: 40 KB (-0.5*norm) (+24 KB pad)
    //   wsK @ 0x170000: N*NSPLIT*LK u32 = 5.12 MB
    const size_t oXB = 0;
    const size_t oXX = 0x150000;
    const size_t oXH = 0x160000;
    const size_t oWK = 0x170000;
    __bf16* xbA = (__bf16*)((char*)d_ws + oXB);
    float*  xxf = (float*)((char*)d_ws + oXX);
    float*  xxh = (float*)((char*)d_ws + oXH);
    u32*    wsK = (u32*)((char*)d_ws + oWK);

    const int prepThreads = NTILES * 2 * 64 + N;         // 90000
    prep<<<(prepThreads + 255) / 256, 256, 0, stream>>>(x, xbA, xxf, xxh, N);

    long long totalF4 = (long long)out_size / 4;         // 25e6
    // 63 supergroups of 48 blocks = 3024 total: 504 zero (8-consecutive
    // bursts -> all XCDs) + 2520 compute slots (>= NCOMP=2512).
    const int nBlocksTotal = 3024;
    const int nZero = 504;
    int f4PerZ = (int)((totalF4 + nZero - 1) / nZero);   // ~49604
    topk_zero_mfma<<<nBlocksTotal, 256, 0, stream>>>(
        xbA, xxh, N, wsK, out, totalF4, nZero, f4PerZ);

    rescore_scatter<<<ROWBLK, 256, 0, stream>>>(wsK, x, xxf, out, N);
}

// Round 6
// 430.452 us; speedup vs baseline: 1.3204x; 1.0343x over previous
//
#include <hip/hip_runtime.h>

#define D 64
#define K 5
#define LK 8                  // per-lane / per-split candidate list length
#define GK 12                 // global candidates rescored per row
#define NSPLIT 16
#define NTILES 625            // 10000 / 16 exactly
#define RWAVE 4               // row-tiles (16 rows each) per wave -> 64 rows/wave
#define RBLK 40               // ceil(10000/256) row-blocks (256 rows per block)
#define NCOMP (RBLK * NSPLIT) // 640 compute blocks
#define ROWBLK 157            // rescore kernel: ceil(10000/64)
typedef unsigned int u32;
typedef unsigned long long u64;
typedef __bf16 bf16x8 __attribute__((ext_vector_type(8)));
typedef float  f32x4v __attribute__((ext_vector_type(4)));

// v_med3_u32 (GCN3+; no HIP builtin)
__device__ __forceinline__ u32 med3u(u32 a, u32 b, u32 c) {
    u32 r;
    asm("v_med3_u32 %0, %1, %2, %3" : "=v"(r) : "v"(a), "v"(b), "v"(c));
    return r;
}

// ---- u32 key: [31:14] = top bits of FULL monotone fp32 map, [13:0] = 0x3FFF-idx
// (== (~idx)&0x3FFF for idx<16384). bigger key == (bigger value, then lower idx).
__device__ __forceinline__ int idx32(u32 key) { return (int)((~key) & 0x3FFFu); }

// exact final key (value, then lower idx)
__device__ __forceinline__ u64 packKV(float v, int idx) {
    u32 u = __float_as_uint(v);
    u ^= ((u32)((int)u >> 31)) | 0x80000000u;
    return ((u64)u << 32) | (u32)(~idx);
}
__device__ __forceinline__ float unpackV(u64 key) {
    u32 hu = (u32)(key >> 32);
    return (hu & 0x80000000u) ? __uint_as_float(hu & 0x7fffffffu)
                              : __uint_as_float(~hu);
}

// branchless merge of two sorted-desc lists, keep first LO into a[]
template<int LO, int LA, int LB, typename T>
__device__ __forceinline__ void mergeKeep(T a[LA], const T b[LB]) {
    T A[LA], B[LB], out[LO];
#pragma unroll
    for (int i = 0; i < LA; ++i) A[i] = a[i];
#pragma unroll
    for (int i = 0; i < LB; ++i) B[i] = b[i];
#pragma unroll
    for (int m = 0; m < LO; ++m) {
        bool ta = A[0] >= B[0];
        out[m] = ta ? A[0] : B[0];
#pragma unroll
        for (int i = 0; i < LA - 1; ++i) A[i] = ta ? A[i + 1] : A[i];
        A[LA - 1] = ta ? (T)0 : A[LA - 1];
#pragma unroll
        for (int i = 0; i < LB - 1; ++i) B[i] = ta ? B[i] : B[i + 1];
        B[LB - 1] = ta ? B[LB - 1] : (T)0;
    }
#pragma unroll
    for (int m = 0; m < LO; ++m) a[m] = out[m];
}

// ---------------------------------------------------------------------------
// Prep: repack x into MFMA-fragment order + row norms (raw and -0.5x for the
// MFMA C-operand fold).
// xbA[tile][khalf][lane][8 bf16]: lane = q*16+r holds x[tile*16+r][kh*32+q*8..+8).
// ---------------------------------------------------------------------------
__global__ __launch_bounds__(256) void prep(
    const float* __restrict__ x, __bf16* __restrict__ xbA,
    float* __restrict__ xxf, float* __restrict__ xxh, int N)
{
    int g = blockIdx.x * 256 + threadIdx.x;
    const int REPACK = NTILES * 2 * 64;          // 80000
    if (g < REPACK) {
        int tile = g >> 7;
        int rem  = g & 127;
        int kh   = rem >> 6;
        int lane = rem & 63;
        int q = lane >> 4, r = lane & 15;
        int row = tile * 16 + r;
        int k0  = kh * 32 + q * 8;
        const float4* p = (const float4*)(x + (size_t)row * D + k0);
        float4 v0 = p[0], v1 = p[1];
        bf16x8 o;
        o[0] = (__bf16)v0.x; o[1] = (__bf16)v0.y; o[2] = (__bf16)v0.z; o[3] = (__bf16)v0.w;
        o[4] = (__bf16)v1.x; o[5] = (__bf16)v1.y; o[6] = (__bf16)v1.z; o[7] = (__bf16)v1.w;
        ((bf16x8*)xbA)[g] = o;
        return;
    }
    int i = g - REPACK;
    if (i >= N) return;
    const float4* p = (const float4*)(x + (size_t)i * D);
    float s = 0.f;
#pragma unroll
    for (int t = 0; t < 16; ++t) {
        float4 v = p[t];
        s += v.x * v.x + v.y * v.y + v.z * v.z + v.w * v.w;
    }
    xxf[i] = s;
    xxh[i] = -0.5f * s;
}

// ---------------------------------------------------------------------------
// Round-6: 64 query-rows per wave (4 B-tiles + 4 top-8 lists resident).
// Rationale: r3/r4/r5 falsified latency-, placement-, and issue-width-bound
// theories; measured ~900 cyc/iter of unattributed per-iteration wall cost.
// 4x fatter iterations amortize it: wave-iters 393K -> 100K, A-loads per
// candidate /4, per-candidate insert cost unchanged (that floor is ~20us).
// Grid: 16 supergroups of 48 = 768 blocks = 128 zero (8-consecutive bursts
// -> all XCDs, plain dwordx4 stores) + 640 compute. All co-resident at t=0.
// ---------------------------------------------------------------------------
__global__ __launch_bounds__(256) void topk_zero_mfma(
    const __bf16* __restrict__ xbA, const float* __restrict__ xxh, int N,
    u32* __restrict__ wsK, float* __restrict__ outZ, long long totalF4,
    int nZero, int f4PerZ)
{
    const int bx  = blockIdx.x;
    const int tid = threadIdx.x;
    const int g8  = bx >> 3;                     // group of 8 consecutive blocks
    const int r8  = bx & 7;

    if (g8 % 6 == 0) {
        // ---------------- zero block (plain streaming stores) ----------------
        int zid = (g8 / 6) * 8 + r8;
        if (zid >= nZero) return;
        long long s = (long long)zid * f4PerZ;
        long long e = s + f4PerZ; if (e > totalF4) e = totalF4;
        const f32x4v z = {0.f, 0.f, 0.f, 0.f};
        for (long long i = s + tid; i < e; i += 256)
            *(f32x4v*)(outZ + 4 * i) = z;
        return;
    }

    // ---------------- compute block ----------------
    const int cid = bx - (g8 / 6 + 1) * 8;       // dense index over non-zero blocks
    if (cid >= NCOMP) return;
    const int split = cid / RBLK;                // 0..15
    const int rb    = cid - split * RBLK;        // 0..39

    const int lane = tid & 63;
    const int wave = tid >> 6;
    const int l15  = lane & 15;
    const int q    = lane >> 4;                  // col quad
    const int r0   = rb * 256 + wave * 64;       // first of this wave's 64 rows

    const bf16x8* fb = (const bf16x8*)xbA;       // fragment base, 128 per tile

    // B fragments: 4 row-tiles (clamped at the table end for the tail block)
    bf16x8 Bf[RWAVE][2];
#pragma unroll
    for (int l = 0; l < RWAVE; ++l) {
        int bt = (r0 >> 4) + l; if (bt > NTILES - 1) bt = NTILES - 1;
        Bf[l][0] = fb[bt * 128 + lane];
        Bf[l][1] = fb[bt * 128 + 64 + lane];
    }

    // pointer-bumped loop state
    const bf16x8* ap = fb + (size_t)split * 128 + lane;
    const float* xhp = xxh + split * 16 + q * 4;
    u32 base16k = 0x3FFFu - (u32)(split * 16 + q * 4);   // 0x3FFF - cbase
    const int apBump = NSPLIT * 128;             // 2048 fragments
    const int xcBump = NSPLIT * 16;              // 256 floats

    u32 L[RWAVE][LK];
#pragma unroll
    for (int l = 0; l < RWAVE; ++l)
#pragma unroll
        for (int m = 0; m < LK; ++m) L[l][m] = 0u;   // 0 < any real packed key

    // 1-deep software pipeline; prefetch overruns <=16 tiles (32 KB) past
    // xbA and ~1 KB past xxh — workspace pads cover both.
    bf16x8 A0 = ap[0];
    bf16x8 A1 = ap[64];
    f32x4v xh = *(const f32x4v*)xhp;

    for (int t = split; t < NTILES; t += NSPLIT) {
        ap += apBump; xhp += xcBump;
        const bf16x8 nA0 = ap[0];
        const bf16x8 nA1 = ap[64];
        const f32x4v nxh = *(const f32x4v*)xhp;

#pragma unroll
        for (int l = 0; l < RWAVE; ++l) {
            f32x4v acc = xh;                      // C init = -0.5*||xj||^2
            acc = __builtin_amdgcn_mfma_f32_16x16x32_bf16(A0, Bf[l][0], acc, 0, 0, 0);
            acc = __builtin_amdgcn_mfma_f32_16x16x32_bf16(A1, Bf[l][1], acc, 0, 0, 0);

            // monotone key map (5 ops) + med3 insertion (8 ops) per candidate
#pragma unroll
            for (int v = 0; v < 4; ++v) {
                u32 u = __float_as_uint(acc[v]);
                u ^= ((u32)((int)u >> 31)) | 0x80000000u;
                u32 key = (u & 0xFFFFC000u) | (base16k - (u32)v);
                u32 n0 = max(L[l][0], key);
                u32 n1 = med3u(L[l][0], L[l][1], key);
                u32 n2 = med3u(L[l][1], L[l][2], key);
                u32 n3 = med3u(L[l][2], L[l][3], key);
                u32 n4 = med3u(L[l][3], L[l][4], key);
                u32 n5 = med3u(L[l][4], L[l][5], key);
                u32 n6 = med3u(L[l][5], L[l][6], key);
                u32 n7 = med3u(L[l][6], L[l][7], key);
                L[l][0]=n0; L[l][1]=n1; L[l][2]=n2; L[l][3]=n3;
                L[l][4]=n4; L[l][5]=n5; L[l][6]=n6; L[l][7]=n7;
            }
        }
        base16k -= (u32)xcBump;
        A0 = nA0; A1 = nA1; xh = nxh;
    }

    // per row-tile: butterfly merge across the 4 quads sharing a row, then
    // lane<16 writes that row's split-list to wsK
#pragma unroll
    for (int l = 0; l < RWAVE; ++l) {
#pragma unroll
        for (int mask = 16; mask <= 32; mask <<= 1) {
            u32 P[LK];
#pragma unroll
            for (int m = 0; m < LK; ++m) P[m] = (u32)__shfl_xor((int)L[l][m], mask);
            mergeKeep<LK, LK, LK, u32>(L[l], P);
        }
        if (lane < 16) {
            int row = r0 + l * 16 + l15;
            if (row < N) {
                u32* dst = wsK + ((size_t)row * NSPLIT + split) * LK;
#pragma unroll
                for (int m = 0; m < LK; ++m) dst[m] = L[l][m];
            }
        }
    }
}

// ---------------------------------------------------------------------------
// 4 lanes per row. Each lane merges 4 split-lists (u32); 2 shfl_xor
// butterflies give the global bf16-top-12. Each lane rescores 3 candidates in
// exact fp32; final top-5 via exact packed-u64 butterfly (== reference
// tie-break). Lane 0 of each row does the symmetric atomic scatter.
// ---------------------------------------------------------------------------
__global__ __launch_bounds__(256) void rescore_scatter(
    const u32* __restrict__ wsK, const float* __restrict__ x, const float* __restrict__ xxf,
    float* __restrict__ out, int N)
{
    const int lane = threadIdx.x & 63;
    const int wave = threadIdx.x >> 6;
    const int sub  = lane & 3;
    const int row  = blockIdx.x * 64 + wave * 16 + (lane >> 2);
    const bool vrow = (row < N);
    const int rr = vrow ? row : 0;

    // merge my 4 lists, then butterfly to global top-12
    u32 cur[GK];
    {
        const u32* Lp = wsK + ((size_t)rr * NSPLIT + 4 * sub) * LK;
#pragma unroll
        for (int m = 0; m < LK; ++m) cur[m] = Lp[m];
#pragma unroll
        for (int m = LK; m < GK; ++m) cur[m] = 0u;
#pragma unroll
        for (int l = 1; l < 4; ++l) {
            u32 b[LK];
#pragma unroll
            for (int m = 0; m < LK; ++m) b[m] = Lp[l * LK + m];
            mergeKeep<GK, GK, LK, u32>(cur, b);
        }
    }
#pragma unroll
    for (int mask = 1; mask <= 2; mask <<= 1) {
        u32 P[GK];
#pragma unroll
        for (int m = 0; m < GK; ++m) P[m] = (u32)__shfl_xor((int)cur[m], mask);
        mergeKeep<GK, GK, GK, u32>(cur, P);
    }

    // exact fp32 rescore of my 3 candidates
    const float nxi = xxf[rr];
    int   cj[3]; bool cval[3];
    float d[3] = {0.f, 0.f, 0.f};
    const f32x4v* pj[3];
#pragma unroll
    for (int c = 0; c < 3; ++c) {
        int j = idx32(cur[sub * 3 + c]);
        cval[c] = (j < N) && (cur[sub * 3 + c] != 0u);
        cj[c] = cval[c] ? j : 0;
        pj[c] = (const f32x4v*)(x + (size_t)cj[c] * D);
    }
    const f32x4v* xip = (const f32x4v*)(x + (size_t)rr * D);
#pragma unroll
    for (int t = 0; t < 16; ++t) {
        const f32x4v xv = xip[t];
#pragma unroll
        for (int c = 0; c < 3; ++c) {
            const f32x4v pv = pj[c][t];
            d[c] = fmaf(xv[0], pv[0], d[c]);
            d[c] = fmaf(xv[1], pv[1], d[c]);
            d[c] = fmaf(xv[2], pv[2], d[c]);
            d[c] = fmaf(xv[3], pv[3], d[c]);
        }
    }
    u64 F[K];
#pragma unroll
    for (int c = 0; c < 3; ++c) {
        float val = 2.f * d[c] - nxi - xxf[cj[c]];
        F[c] = cval[c] ? packKV(val, cj[c]) : 0ull;
    }
    F[3] = 0ull; F[4] = 0ull;
    // sort first 3 desc
    { u64 a0=F[0],a1=F[1],a2=F[2];
      if (a0 < a1) { u64 t0=a0; a0=a1; a1=t0; }
      if (a1 < a2) { u64 t0=a1; a1=a2; a2=t0; }
      if (a0 < a1) { u64 t0=a0; a0=a1; a1=t0; }
      F[0]=a0; F[1]=a1; F[2]=a2; }
#pragma unroll
    for (int mask = 1; mask <= 2; mask <<= 1) {
        u64 P[K];
#pragma unroll
        for (int m = 0; m < K; ++m) P[m] = __shfl_xor(F[m], mask);
        mergeKeep<K, K, K, u64>(F, P);
    }

    if (sub == 0 && vrow) {
#pragma unroll
        for (int m = 0; m < K; ++m) {
            int j = (int)(~(u32)F[m]);
            if ((unsigned)j < (unsigned)N && j != row) {
                float v = unpackV(F[m]);
                atomicAdd(out + (size_t)row * N + j, v);
                atomicAdd(out + (size_t)j * N + row, v);
            }
        }
    }
}

// ---------------------------------------------------------------------------
extern "C" void kernel_launch(void* const* d_in, const int* in_sizes, int n_in,
                              void* d_out, int out_size, void* d_ws, size_t ws_size,
                              hipStream_t stream) {
    const float* x = (const float*)d_in[0];
    const int N = in_sizes[0] / D;          // 10000
    float* out = (float*)d_out;

    // Workspace layout (fixed offsets; pads cover the 1-deep prefetch
    // overrun: <=16 tiles = 32 KB past xbA, ~1 KB past xxh):
    //   xbA @ 0x000000: 625*128*16B = 1.28 MB (+pad)  -> ends < 0x150000
    //   xxf @ 0x150000: 40 KB raw norms
    //   xxh @ 0x160000: 40 KB (-0.5*norm) (+24 KB pad)
    //   wsK @ 0x170000: N*NSPLIT*LK u32 = 5.12 MB
    const size_t oXB = 0;
    const size_t oXX = 0x150000;
    const size_t oXH = 0x160000;
    const size_t oWK = 0x170000;
    __bf16* xbA = (__bf16*)((char*)d_ws + oXB);
    float*  xxf = (float*)((char*)d_ws + oXX);
    float*  xxh = (float*)((char*)d_ws + oXH);
    u32*    wsK = (u32*)((char*)d_ws + oWK);

    const int prepThreads = NTILES * 2 * 64 + N;         // 90000
    prep<<<(prepThreads + 255) / 256, 256, 0, stream>>>(x, xbA, xxf, xxh, N);

    long long totalF4 = (long long)out_size / 4;         // 25e6
    // 16 supergroups of 48 blocks = 768 total: 128 zero (8-consecutive
    // bursts -> all XCDs) + 640 compute (= NCOMP exactly).
    const int nBlocksTotal = 768;
    const int nZero = 128;
    int f4PerZ = (int)((totalF4 + nZero - 1) / nZero);   // ~195313
    topk_zero_mfma<<<nBlocksTotal, 256, 0, stream>>>(
        xbA, xxh, N, wsK, out, totalF4, nZero, f4PerZ);

    rescore_scatter<<<ROWBLK, 256, 0, stream>>>(wsK, x, xxf, out, N);
}

// Round 7
// 421.973 us; speedup vs baseline: 1.3470x; 1.0201x over previous
//
#include <hip/hip_runtime.h>

#define D 64
#define K 5
#define LK 8                  // per-lane / per-split candidate list length
#define GK 12                 // global candidates rescored per row
#define NSPLIT 16
#define NTILES 625            // 10000 / 16 exactly
#define RWAVE 4               // row-tiles (16 rows each) per wave -> 64 rows/wave
#define RBLK 40               // ceil(10000/256) row-blocks (256 rows per block)
#define NCOMP (RBLK * NSPLIT) // 640 compute blocks (== the whole grid now)
#define ROWBLK 157            // rescore kernel: ceil(10000/64)
typedef unsigned int u32;
typedef unsigned long long u64;
typedef __bf16 bf16x8 __attribute__((ext_vector_type(8)));
typedef float  f32x4v __attribute__((ext_vector_type(4)));

// v_med3_u32 (GCN3+; no HIP builtin)
__device__ __forceinline__ u32 med3u(u32 a, u32 b, u32 c) {
    u32 r;
    asm("v_med3_u32 %0, %1, %2, %3" : "=v"(r) : "v"(a), "v"(b), "v"(c));
    return r;
}

// ---- u32 key: [31:14] = top bits of FULL monotone fp32 map, [13:0] = 0x3FFF-idx
// (== (~idx)&0x3FFF for idx<16384). bigger key == (bigger value, then lower idx).
__device__ __forceinline__ int idx32(u32 key) { return (int)((~key) & 0x3FFFu); }

// exact final key (value, then lower idx)
__device__ __forceinline__ u64 packKV(float v, int idx) {
    u32 u = __float_as_uint(v);
    u ^= ((u32)((int)u >> 31)) | 0x80000000u;
    return ((u64)u << 32) | (u32)(~idx);
}
__device__ __forceinline__ float unpackV(u64 key) {
    u32 hu = (u32)(key >> 32);
    return (hu & 0x80000000u) ? __uint_as_float(hu & 0x7fffffffu)
                              : __uint_as_float(~hu);
}

// branchless merge of two sorted-desc lists, keep first LO into a[]
template<int LO, int LA, int LB, typename T>
__device__ __forceinline__ void mergeKeep(T a[LA], const T b[LB]) {
    T A[LA], B[LB], out[LO];
#pragma unroll
    for (int i = 0; i < LA; ++i) A[i] = a[i];
#pragma unroll
    for (int i = 0; i < LB; ++i) B[i] = b[i];
#pragma unroll
    for (int m = 0; m < LO; ++m) {
        bool ta = A[0] >= B[0];
        out[m] = ta ? A[0] : B[0];
#pragma unroll
        for (int i = 0; i < LA - 1; ++i) A[i] = ta ? A[i + 1] : A[i];
        A[LA - 1] = ta ? (T)0 : A[LA - 1];
#pragma unroll
        for (int i = 0; i < LB - 1; ++i) B[i] = ta ? B[i] : B[i + 1];
        B[LB - 1] = ta ? B[LB - 1] : (T)0;
    }
#pragma unroll
    for (int m = 0; m < LO; ++m) a[m] = out[m];
}

// ---------------------------------------------------------------------------
// Prep: repack x into MFMA-fragment order + row norms (raw and -0.5x for the
// MFMA C-operand fold).
// xbA[tile][khalf][lane][8 bf16]: lane = q*16+r holds x[tile*16+r][kh*32+q*8..+8).
// ---------------------------------------------------------------------------
__global__ __launch_bounds__(256) void prep(
    const float* __restrict__ x, __bf16* __restrict__ xbA,
    float* __restrict__ xxf, float* __restrict__ xxh, int N)
{
    int g = blockIdx.x * 256 + threadIdx.x;
    const int REPACK = NTILES * 2 * 64;          // 80000
    if (g < REPACK) {
        int tile = g >> 7;
        int rem  = g & 127;
        int kh   = rem >> 6;
        int lane = rem & 63;
        int q = lane >> 4, r = lane & 15;
        int row = tile * 16 + r;
        int k0  = kh * 32 + q * 8;
        const float4* p = (const float4*)(x + (size_t)row * D + k0);
        float4 v0 = p[0], v1 = p[1];
        bf16x8 o;
        o[0] = (__bf16)v0.x; o[1] = (__bf16)v0.y; o[2] = (__bf16)v0.z; o[3] = (__bf16)v0.w;
        o[4] = (__bf16)v1.x; o[5] = (__bf16)v1.y; o[6] = (__bf16)v1.z; o[7] = (__bf16)v1.w;
        ((bf16x8*)xbA)[g] = o;
        return;
    }
    int i = g - REPACK;
    if (i >= N) return;
    const float4* p = (const float4*)(x + (size_t)i * D);
    float s = 0.f;
#pragma unroll
    for (int t = 0; t < 16; ++t) {
        float4 v = p[t];
        s += v.x * v.x + v.y * v.y + v.z * v.z + v.w * v.w;
    }
    xxf[i] = s;
    xxh[i] = -0.5f * s;
}

// ---------------------------------------------------------------------------
// Round-7: STORE-FUSED zeroing. No dedicated zero blocks — every compute
// block streams its own contiguous 625-KB slice of out with 4 guarded NT
// stores per K-iteration (39 iters x 1024 f4/block-iter = 39936 >= 39063
// needed; guards cover the tail; every split has >=39 loop trips).
// Rationale: r6's 128 writer-blocks capped the write leg at ~128 CUs' worth
// of HBM write allocation (~3 TB/s -> ~130 us). With all 256 CUs writing,
// the 400 MB zero runs at full rate (~66 us) and hides under the scan.
// vmcnt ordering: each iter's A-prefetch is issued BEFORE its stores, so
// the A-wait never waits on younger stores; store-ack hides under the
// ~440-cyc iteration. NT keeps the write stream out of L2 (A-table stays
// resident). Scan path identical to r6 (RWAVE=4, key fold, med3 network).
// ---------------------------------------------------------------------------
__global__ __launch_bounds__(256) void topk_zero_mfma(
    const __bf16* __restrict__ xbA, const float* __restrict__ xxh, int N,
    u32* __restrict__ wsK, float* __restrict__ outZ, long long totalF4,
    int f4PerB)
{
    const int bx  = blockIdx.x;
    const int tid = threadIdx.x;

    const int split = bx / RBLK;                 // 0..15
    const int rb    = bx - split * RBLK;         // 0..39

    const int lane = tid & 63;
    const int wave = tid >> 6;
    const int l15  = lane & 15;
    const int q    = lane >> 4;                  // col quad
    const int r0   = rb * 256 + wave * 64;       // first of this wave's 64 rows

    // my zero slice [zs, ze) in float4 units
    long long zi = (long long)bx * f4PerB + tid;
    long long ze = (long long)(bx + 1) * f4PerB;
    if (ze > totalF4) ze = totalF4;
    const f32x4v zv = {0.f, 0.f, 0.f, 0.f};

    const bf16x8* fb = (const bf16x8*)xbA;       // fragment base, 128 per tile

    // B fragments: 4 row-tiles (clamped at the table end for the tail block)
    bf16x8 Bf[RWAVE][2];
#pragma unroll
    for (int l = 0; l < RWAVE; ++l) {
        int bt = (r0 >> 4) + l; if (bt > NTILES - 1) bt = NTILES - 1;
        Bf[l][0] = fb[bt * 128 + lane];
        Bf[l][1] = fb[bt * 128 + 64 + lane];
    }

    // pointer-bumped loop state
    const bf16x8* ap = fb + (size_t)split * 128 + lane;
    const float* xhp = xxh + split * 16 + q * 4;
    u32 base16k = 0x3FFFu - (u32)(split * 16 + q * 4);   // 0x3FFF - cbase
    const int apBump = NSPLIT * 128;             // 2048 fragments
    const int xcBump = NSPLIT * 16;              // 256 floats

    u32 L[RWAVE][LK];
#pragma unroll
    for (int l = 0; l < RWAVE; ++l)
#pragma unroll
        for (int m = 0; m < LK; ++m) L[l][m] = 0u;   // 0 < any real packed key

    // 1-deep software pipeline; prefetch overruns <=16 tiles (32 KB) past
    // xbA and ~1 KB past xxh — workspace pads cover both.
    bf16x8 A0 = ap[0];
    bf16x8 A1 = ap[64];
    f32x4v xh = *(const f32x4v*)xhp;

    for (int t = split; t < NTILES; t += NSPLIT) {
        ap += apBump; xhp += xcBump;
        const bf16x8 nA0 = ap[0];
        const bf16x8 nA1 = ap[64];
        const f32x4v nxh = *(const f32x4v*)xhp;

#pragma unroll
        for (int l = 0; l < RWAVE; ++l) {
            f32x4v acc = xh;                      // C init = -0.5*||xj||^2
            acc = __builtin_amdgcn_mfma_f32_16x16x32_bf16(A0, Bf[l][0], acc, 0, 0, 0);
            acc = __builtin_amdgcn_mfma_f32_16x16x32_bf16(A1, Bf[l][1], acc, 0, 0, 0);

            // monotone key map (5 ops) + med3 insertion (8 ops) per candidate
#pragma unroll
            for (int v = 0; v < 4; ++v) {
                u32 u = __float_as_uint(acc[v]);
                u ^= ((u32)((int)u >> 31)) | 0x80000000u;
                u32 key = (u & 0xFFFFC000u) | (base16k - (u32)v);
                u32 n0 = max(L[l][0], key);
                u32 n1 = med3u(L[l][0], L[l][1], key);
                u32 n2 = med3u(L[l][1], L[l][2], key);
                u32 n3 = med3u(L[l][2], L[l][3], key);
                u32 n4 = med3u(L[l][3], L[l][4], key);
                u32 n5 = med3u(L[l][4], L[l][5], key);
                u32 n6 = med3u(L[l][5], L[l][6], key);
                u32 n7 = med3u(L[l][6], L[l][7], key);
                L[l][0]=n0; L[l][1]=n1; L[l][2]=n2; L[l][3]=n3;
                L[l][4]=n4; L[l][5]=n5; L[l][6]=n6; L[l][7]=n7;
            }
        }
        base16k -= (u32)xcBump;
        A0 = nA0; A1 = nA1; xh = nxh;

        // zero-stream slice: 4 guarded NT stores (1024 f4 per block-iter)
#pragma unroll
        for (int j = 0; j < 4; ++j) {
            if (zi < ze)
                __builtin_nontemporal_store(zv, (f32x4v*)(outZ + 4 * zi));
            zi += 256;
        }
    }

    // per row-tile: butterfly merge across the 4 quads sharing a row, then
    // lane<16 writes that row's split-list to wsK
#pragma unroll
    for (int l = 0; l < RWAVE; ++l) {
#pragma unroll
        for (int mask = 16; mask <= 32; mask <<= 1) {
            u32 P[LK];
#pragma unroll
            for (int m = 0; m < LK; ++m) P[m] = (u32)__shfl_xor((int)L[l][m], mask);
            mergeKeep<LK, LK, LK, u32>(L[l], P);
        }
        if (lane < 16) {
            int row = r0 + l * 16 + l15;
            if (row < N) {
                u32* dst = wsK + ((size_t)row * NSPLIT + split) * LK;
#pragma unroll
                for (int m = 0; m < LK; ++m) dst[m] = L[l][m];
            }
        }
    }
}

// ---------------------------------------------------------------------------
// 4 lanes per row. Each lane merges 4 split-lists (u32); 2 shfl_xor
// butterflies give the global bf16-top-12. Each lane rescores 3 candidates in
// exact fp32; final top-5 via exact packed-u64 butterfly (== reference
// tie-break). Lane 0 of each row does the symmetric atomic scatter.
// ---------------------------------------------------------------------------
__global__ __launch_bounds__(256) void rescore_scatter(
    const u32* __restrict__ wsK, const float* __restrict__ x, const float* __restrict__ xxf,
    float* __restrict__ out, int N)
{
    const int lane = threadIdx.x & 63;
    const int wave = threadIdx.x >> 6;
    const int sub  = lane & 3;
    const int row  = blockIdx.x * 64 + wave * 16 + (lane >> 2);
    const bool vrow = (row < N);
    const int rr = vrow ? row : 0;

    // merge my 4 lists, then butterfly to global top-12
    u32 cur[GK];
    {
        const u32* Lp = wsK + ((size_t)rr * NSPLIT + 4 * sub) * LK;
#pragma unroll
        for (int m = 0; m < LK; ++m) cur[m] = Lp[m];
#pragma unroll
        for (int m = LK; m < GK; ++m) cur[m] = 0u;
#pragma unroll
        for (int l = 1; l < 4; ++l) {
            u32 b[LK];
#pragma unroll
            for (int m = 0; m < LK; ++m) b[m] = Lp[l * LK + m];
            mergeKeep<GK, GK, LK, u32>(cur, b);
        }
    }
#pragma unroll
    for (int mask = 1; mask <= 2; mask <<= 1) {
        u32 P[GK];
#pragma unroll
        for (int m = 0; m < GK; ++m) P[m] = (u32)__shfl_xor((int)cur[m], mask);
        mergeKeep<GK, GK, GK, u32>(cur, P);
    }

    // exact fp32 rescore of my 3 candidates
    const float nxi = xxf[rr];
    int   cj[3]; bool cval[3];
    float d[3] = {0.f, 0.f, 0.f};
    const f32x4v* pj[3];
#pragma unroll
    for (int c = 0; c < 3; ++c) {
        int j = idx32(cur[sub * 3 + c]);
        cval[c] = (j < N) && (cur[sub * 3 + c] != 0u);
        cj[c] = cval[c] ? j : 0;
        pj[c] = (const f32x4v*)(x + (size_t)cj[c] * D);
    }
    const f32x4v* xip = (const f32x4v*)(x + (size_t)rr * D);
#pragma unroll
    for (int t = 0; t < 16; ++t) {
        const f32x4v xv = xip[t];
#pragma unroll
        for (int c = 0; c < 3; ++c) {
            const f32x4v pv = pj[c][t];
            d[c] = fmaf(xv[0], pv[0], d[c]);
            d[c] = fmaf(xv[1], pv[1], d[c]);
            d[c] = fmaf(xv[2], pv[2], d[c]);
            d[c] = fmaf(xv[3], pv[3], d[c]);
        }
    }
    u64 F[K];
#pragma unroll
    for (int c = 0; c < 3; ++c) {
        float val = 2.f * d[c] - nxi - xxf[cj[c]];
        F[c] = cval[c] ? packKV(val, cj[c]) : 0ull;
    }
    F[3] = 0ull; F[4] = 0ull;
    // sort first 3 desc
    { u64 a0=F[0],a1=F[1],a2=F[2];
      if (a0 < a1) { u64 t0=a0; a0=a1; a1=t0; }
      if (a1 < a2) { u64 t0=a1; a1=a2; a2=t0; }
      if (a0 < a1) { u64 t0=a0; a0=a1; a1=t0; }
      F[0]=a0; F[1]=a1; F[2]=a2; }
#pragma unroll
    for (int mask = 1; mask <= 2; mask <<= 1) {
        u64 P[K];
#pragma unroll
        for (int m = 0; m < K; ++m) P[m] = __shfl_xor(F[m], mask);
        mergeKeep<K, K, K, u64>(F, P);
    }

    if (sub == 0 && vrow) {
#pragma unroll
        for (int m = 0; m < K; ++m) {
            int j = (int)(~(u32)F[m]);
            if ((unsigned)j < (unsigned)N && j != row) {
                float v = unpackV(F[m]);
                atomicAdd(out + (size_t)row * N + j, v);
                atomicAdd(out + (size_t)j * N + row, v);
            }
        }
    }
}

// ---------------------------------------------------------------------------
extern "C" void kernel_launch(void* const* d_in, const int* in_sizes, int n_in,
                              void* d_out, int out_size, void* d_ws, size_t ws_size,
                              hipStream_t stream) {
    const float* x = (const float*)d_in[0];
    const int N = in_sizes[0] / D;          // 10000
    float* out = (float*)d_out;

    // Workspace layout (fixed offsets; pads cover the 1-deep prefetch
    // overrun: <=16 tiles = 32 KB past xbA, ~1 KB past xxh):
    //   xbA @ 0x000000: 625*128*16B = 1.28 MB (+pad)  -> ends < 0x150000
    //   xxf @ 0x150000: 40 KB raw norms
    //   xxh @ 0x160000: 40 KB (-0.5*norm) (+24 KB pad)
    //   wsK @ 0x170000: N*NSPLIT*LK u32 = 5.12 MB
    const size_t oXB = 0;
    const size_t oXX = 0x150000;
    const size_t oXH = 0x160000;
    const size_t oWK = 0x170000;
    __bf16* xbA = (__bf16*)((char*)d_ws + oXB);
    float*  xxf = (float*)((char*)d_ws + oXX);
    float*  xxh = (float*)((char*)d_ws + oXH);
    u32*    wsK = (u32*)((char*)d_ws + oWK);

    const int prepThreads = NTILES * 2 * 64 + N;         // 90000
    prep<<<(prepThreads + 255) / 256, 256, 0, stream>>>(x, xbA, xxf, xxh, N);

    long long totalF4 = (long long)out_size / 16;        // 25e6 float4
    int f4PerB = (int)((totalF4 + NCOMP - 1) / NCOMP);   // 39063
    topk_zero_mfma<<<NCOMP, 256, 0, stream>>>(
        xbA, xxh, N, wsK, out, totalF4, f4PerB);

    rescore_scatter<<<ROWBLK, 256, 0, stream>>>(wsK, x, xxf, out, N);
}

// Round 8
// 420.023 us; speedup vs baseline: 1.3532x; 1.0046x over previous
//
#include <hip/hip_runtime.h>

#define D 64
#define K 5
#define LK 8                  // per-lane / per-split candidate list length
#define GK 12                 // global candidates rescored per row
#define NSPLIT 16
#define NTILES 625            // 10000 / 16 exactly
#define RWAVE 4               // row-tiles (16 rows each) per wave -> 64 rows/wave
#define RBLK 40               // ceil(10000/256) row-blocks (256 rows per block)
#define NCOMP (RBLK * NSPLIT) // 640 compute blocks (== the whole grid)
typedef unsigned int u32;
typedef unsigned long long u64;
typedef __bf16 bf16x8 __attribute__((ext_vector_type(8)));
typedef float  f32x4v __attribute__((ext_vector_type(4)));

// v_med3_u32 (GCN3+; no HIP builtin)
__device__ __forceinline__ u32 med3u(u32 a, u32 b, u32 c) {
    u32 r;
    asm("v_med3_u32 %0, %1, %2, %3" : "=v"(r) : "v"(a), "v"(b), "v"(c));
    return r;
}

// ---- u32 key: [31:14] = top bits of FULL monotone fp32 map, [13:0] = 0x3FFF-idx
// (== (~idx)&0x3FFF for idx<16384). bigger key == (bigger value, then lower idx).
__device__ __forceinline__ int idx32(u32 key) { return (int)((~key) & 0x3FFFu); }

// exact final key (value, then lower idx)
__device__ __forceinline__ u64 packKV(float v, int idx) {
    u32 u = __float_as_uint(v);
    u ^= ((u32)((int)u >> 31)) | 0x80000000u;
    return ((u64)u << 32) | (u32)(~idx);
}
__device__ __forceinline__ float unpackV(u64 key) {
    u32 hu = (u32)(key >> 32);
    return (hu & 0x80000000u) ? __uint_as_float(hu & 0x7fffffffu)
                              : __uint_as_float(~hu);
}

// branchless merge of two sorted-desc lists, keep first LO into a[]
template<int LO, int LA, int LB, typename T>
__device__ __forceinline__ void mergeKeep(T a[LA], const T b[LB]) {
    T A[LA], B[LB], out[LO];
#pragma unroll
    for (int i = 0; i < LA; ++i) A[i] = a[i];
#pragma unroll
    for (int i = 0; i < LB; ++i) B[i] = b[i];
#pragma unroll
    for (int m = 0; m < LO; ++m) {
        bool ta = A[0] >= B[0];
        out[m] = ta ? A[0] : B[0];
#pragma unroll
        for (int i = 0; i < LA - 1; ++i) A[i] = ta ? A[i + 1] : A[i];
        A[LA - 1] = ta ? (T)0 : A[LA - 1];
#pragma unroll
        for (int i = 0; i < LB - 1; ++i) B[i] = ta ? B[i] : B[i + 1];
        B[LB - 1] = ta ? B[LB - 1] : (T)0;
    }
#pragma unroll
    for (int m = 0; m < LO; ++m) a[m] = out[m];
}

// ---------------------------------------------------------------------------
// Prep: repack x into MFMA-fragment order + row norms (raw and -0.5x for the
// MFMA C-operand fold).
// xbA[tile][khalf][lane][8 bf16]: lane = q*16+r holds x[tile*16+r][kh*32+q*8..+8).
// ---------------------------------------------------------------------------
__global__ __launch_bounds__(256) void prep(
    const float* __restrict__ x, __bf16* __restrict__ xbA,
    float* __restrict__ xxf, float* __restrict__ xxh, int N)
{
    int g = blockIdx.x * 256 + threadIdx.x;
    const int REPACK = NTILES * 2 * 64;          // 80000
    if (g < REPACK) {
        int tile = g >> 7;
        int rem  = g & 127;
        int kh   = rem >> 6;
        int lane = rem & 63;
        int q = lane >> 4, r = lane & 15;
        int row = tile * 16 + r;
        int k0  = kh * 32 + q * 8;
        const float4* p = (const float4*)(x + (size_t)row * D + k0);
        float4 v0 = p[0], v1 = p[1];
        bf16x8 o;
        o[0] = (__bf16)v0.x; o[1] = (__bf16)v0.y; o[2] = (__bf16)v0.z; o[3] = (__bf16)v0.w;
        o[4] = (__bf16)v1.x; o[5] = (__bf16)v1.y; o[6] = (__bf16)v1.z; o[7] = (__bf16)v1.w;
        ((bf16x8*)xbA)[g] = o;
        return;
    }
    int i = g - REPACK;
    if (i >= N) return;
    const float4* p = (const float4*)(x + (size_t)i * D);
    float s = 0.f;
#pragma unroll
    for (int t = 0; t < 16; ++t) {
        float4 v = p[t];
        s += v.x * v.x + v.y * v.y + v.z * v.z + v.w * v.w;
    }
    xxf[i] = s;
    xxh[i] = -0.5f * s;
}

// ---------------------------------------------------------------------------
// Round-8: store-fused zeroing + 2-DEEP prefetch.
// vmcnt retirement is in-order and counts loads+stores together; with 1-deep
// prefetch each iteration's s_waitcnt for its A-fragments (vmcnt(4)) also
// drains the PREVIOUS iteration's 4 NT stores (HBM ack ~600-900 cyc vs
// ~500-cyc iteration) -> per-iter stall on old writes. Consuming data two
// iterations after issue raises the wait threshold to vmcnt(~11), giving
// stores a full extra iteration to drain before any wave blocks on them.
// (r3's 2-deep null was on the storeless structure - no coupling existed.)
// Everything else identical to r7: 640 blocks, RWAVE=4, 4 guarded NT stores
// per iter (39936 f4-slots >= 39063 needed per block), med3 insert network.
// ---------------------------------------------------------------------------
__global__ __launch_bounds__(256) void topk_zero_mfma(
    const __bf16* __restrict__ xbA, const float* __restrict__ xxh, int N,
    u32* __restrict__ wsK, float* __restrict__ outZ, long long totalF4,
    int f4PerB)
{
    const int bx  = blockIdx.x;
    const int tid = threadIdx.x;

    const int split = bx / RBLK;                 // 0..15
    const int rb    = bx - split * RBLK;         // 0..39

    const int lane = tid & 63;
    const int wave = tid >> 6;
    const int l15  = lane & 15;
    const int q    = lane >> 4;                  // col quad
    const int r0   = rb * 256 + wave * 64;       // first of this wave's 64 rows

    // my zero slice [zi, ze) in float4 units
    long long zi = (long long)bx * f4PerB + tid;
    long long ze = (long long)(bx + 1) * f4PerB;
    if (ze > totalF4) ze = totalF4;
    const f32x4v zv = {0.f, 0.f, 0.f, 0.f};

    const bf16x8* fb = (const bf16x8*)xbA;       // fragment base, 128 per tile

    // B fragments: 4 row-tiles (clamped at the table end for the tail block)
    bf16x8 Bf[RWAVE][2];
#pragma unroll
    for (int l = 0; l < RWAVE; ++l) {
        int bt = (r0 >> 4) + l; if (bt > NTILES - 1) bt = NTILES - 1;
        Bf[l][0] = fb[bt * 128 + lane];
        Bf[l][1] = fb[bt * 128 + 64 + lane];
    }

    // pointer-bumped loop state
    const bf16x8* ap = fb + (size_t)split * 128 + lane;
    const float* xhp = xxh + split * 16 + q * 4;
    u32 base16k = 0x3FFFu - (u32)(split * 16 + q * 4);   // 0x3FFF - cbase
    const int apBump = NSPLIT * 128;             // 2048 fragments
    const int xcBump = NSPLIT * 16;              // 256 floats

    u32 L[RWAVE][LK];
#pragma unroll
    for (int l = 0; l < RWAVE; ++l)
#pragma unroll
        for (int m = 0; m < LK; ++m) L[l][m] = 0u;   // 0 < any real packed key

    // 2-deep software pipeline; prefetch overruns <=32 tiles (64 KB) past
    // xbA and ~2 KB past xxh — workspace pads cover both.
    bf16x8 A0a = ap[0];
    bf16x8 A1a = ap[64];
    f32x4v xha = *(const f32x4v*)xhp;
    ap += apBump; xhp += xcBump;
    bf16x8 A0b = ap[0];
    bf16x8 A1b = ap[64];
    f32x4v xhb = *(const f32x4v*)xhp;

    for (int t = split; t < NTILES; t += NSPLIT) {
        ap += apBump; xhp += xcBump;
        const bf16x8 nA0 = ap[0];
        const bf16x8 nA1 = ap[64];
        const f32x4v nxh = *(const f32x4v*)xhp;

#pragma unroll
        for (int l = 0; l < RWAVE; ++l) {
            f32x4v acc = xha;                     // C init = -0.5*||xj||^2
            acc = __builtin_amdgcn_mfma_f32_16x16x32_bf16(A0a, Bf[l][0], acc, 0, 0, 0);
            acc = __builtin_amdgcn_mfma_f32_16x16x32_bf16(A1a, Bf[l][1], acc, 0, 0, 0);

            // monotone key map (5 ops) + med3 insertion (8 ops) per candidate
#pragma unroll
            for (int v = 0; v < 4; ++v) {
                u32 u = __float_as_uint(acc[v]);
                u ^= ((u32)((int)u >> 31)) | 0x80000000u;
                u32 key = (u & 0xFFFFC000u) | (base16k - (u32)v);
                u32 n0 = max(L[l][0], key);
                u32 n1 = med3u(L[l][0], L[l][1], key);
                u32 n2 = med3u(L[l][1], L[l][2], key);
                u32 n3 = med3u(L[l][2], L[l][3], key);
                u32 n4 = med3u(L[l][3], L[l][4], key);
                u32 n5 = med3u(L[l][4], L[l][5], key);
                u32 n6 = med3u(L[l][5], L[l][6], key);
                u32 n7 = med3u(L[l][6], L[l][7], key);
                L[l][0]=n0; L[l][1]=n1; L[l][2]=n2; L[l][3]=n3;
                L[l][4]=n4; L[l][5]=n5; L[l][6]=n6; L[l][7]=n7;
            }
        }
        base16k -= (u32)xcBump;
        A0a = A0b; A1a = A1b; xha = xhb;
        A0b = nA0; A1b = nA1; xhb = nxh;

        // zero-stream slice: 4 guarded NT stores (1024 f4 per block-iter)
#pragma unroll
        for (int j = 0; j < 4; ++j) {
            if (zi < ze)
                __builtin_nontemporal_store(zv, (f32x4v*)(outZ + 4 * zi));
            zi += 256;
        }
    }

    // per row-tile: butterfly merge across the 4 quads sharing a row, then
    // lane<16 writes that row's split-list to wsK
#pragma unroll
    for (int l = 0; l < RWAVE; ++l) {
#pragma unroll
        for (int mask = 16; mask <= 32; mask <<= 1) {
            u32 P[LK];
#pragma unroll
            for (int m = 0; m < LK; ++m) P[m] = (u32)__shfl_xor((int)L[l][m], mask);
            mergeKeep<LK, LK, LK, u32>(L[l], P);
        }
        if (lane < 16) {
            int row = r0 + l * 16 + l15;
            if (row < N) {
                u32* dst = wsK + ((size_t)row * NSPLIT + split) * LK;
#pragma unroll
                for (int m = 0; m < LK; ++m) dst[m] = L[l][m];
            }
        }
    }
}

// ---------------------------------------------------------------------------
// One wave per block, 16 rows per block (625 blocks): 4 lanes per row.
// Each lane merges 4 split-lists (u32); 2 shfl_xor butterflies give the
// global bf16-top-12. Each lane rescores 3 candidates in exact fp32; final
// top-5 via exact packed-u64 butterfly (== reference tie-break). Lane 0 of
// each row does the symmetric atomic scatter. 64-thread blocks spread the
// atomics/latency over 625 schedulable units instead of 157.
// ---------------------------------------------------------------------------
__global__ __launch_bounds__(64) void rescore_scatter(
    const u32* __restrict__ wsK, const float* __restrict__ x, const float* __restrict__ xxf,
    float* __restrict__ out, int N)
{
    const int lane = threadIdx.x & 63;
    const int sub  = lane & 3;
    const int row  = blockIdx.x * 16 + (lane >> 2);
    const bool vrow = (row < N);
    const int rr = vrow ? row : 0;

    // merge my 4 lists, then butterfly to global top-12
    u32 cur[GK];
    {
        const u32* Lp = wsK + ((size_t)rr * NSPLIT + 4 * sub) * LK;
#pragma unroll
        for (int m = 0; m < LK; ++m) cur[m] = Lp[m];
#pragma unroll
        for (int m = LK; m < GK; ++m) cur[m] = 0u;
#pragma unroll
        for (int l = 1; l < 4; ++l) {
            u32 b[LK];
#pragma unroll
            for (int m = 0; m < LK; ++m) b[m] = Lp[l * LK + m];
            mergeKeep<GK, GK, LK, u32>(cur, b);
        }
    }
#pragma unroll
    for (int mask = 1; mask <= 2; mask <<= 1) {
        u32 P[GK];
#pragma unroll
        for (int m = 0; m < GK; ++m) P[m] = (u32)__shfl_xor((int)cur[m], mask);
        mergeKeep<GK, GK, GK, u32>(cur, P);
    }

    // exact fp32 rescore of my 3 candidates
    const float nxi = xxf[rr];
    int   cj[3]; bool cval[3];
    float d[3] = {0.f, 0.f, 0.f};
    const f32x4v* pj[3];
#pragma unroll
    for (int c = 0; c < 3; ++c) {
        int j = idx32(cur[sub * 3 + c]);
        cval[c] = (j < N) && (cur[sub * 3 + c] != 0u);
        cj[c] = cval[c] ? j : 0;
        pj[c] = (const f32x4v*)(x + (size_t)cj[c] * D);
    }
    const f32x4v* xip = (const f32x4v*)(x + (size_t)rr * D);
#pragma unroll
    for (int t = 0; t < 16; ++t) {
        const f32x4v xv = xip[t];
#pragma unroll
        for (int c = 0; c < 3; ++c) {
            const f32x4v pv = pj[c][t];
            d[c] = fmaf(xv[0], pv[0], d[c]);
            d[c] = fmaf(xv[1], pv[1], d[c]);
            d[c] = fmaf(xv[2], pv[2], d[c]);
            d[c] = fmaf(xv[3], pv[3], d[c]);
        }
    }
    u64 F[K];
#pragma unroll
    for (int c = 0; c < 3; ++c) {
        float val = 2.f * d[c] - nxi - xxf[cj[c]];
        F[c] = cval[c] ? packKV(val, cj[c]) : 0ull;
    }
    F[3] = 0ull; F[4] = 0ull;
    // sort first 3 desc
    { u64 a0=F[0],a1=F[1],a2=F[2];
      if (a0 < a1) { u64 t0=a0; a0=a1; a1=t0; }
      if (a1 < a2) { u64 t0=a1; a1=a2; a2=t0; }
      if (a0 < a1) { u64 t0=a0; a0=a1; a1=t0; }
      F[0]=a0; F[1]=a1; F[2]=a2; }
#pragma unroll
    for (int mask = 1; mask <= 2; mask <<= 1) {
        u64 P[K];
#pragma unroll
        for (int m = 0; m < K; ++m) P[m] = __shfl_xor(F[m], mask);
        mergeKeep<K, K, K, u64>(F, P);
    }

    if (sub == 0 && vrow) {
#pragma unroll
        for (int m = 0; m < K; ++m) {
            int j = (int)(~(u32)F[m]);
            if ((unsigned)j < (unsigned)N && j != row) {
                float v = unpackV(F[m]);
                atomicAdd(out + (size_t)row * N + j, v);
                atomicAdd(out + (size_t)j * N + row, v);
            }
        }
    }
}

// ---------------------------------------------------------------------------
extern "C" void kernel_launch(void* const* d_in, const int* in_sizes, int n_in,
                              void* d_out, int out_size, void* d_ws, size_t ws_size,
                              hipStream_t stream) {
    const float* x = (const float*)d_in[0];
    const int N = in_sizes[0] / D;          // 10000
    float* out = (float*)d_out;

    // Workspace layout (fixed offsets; pads cover the 2-deep prefetch
    // overrun: <=32 tiles = 64 KB past xbA, ~2 KB past xxh):
    //   xbA @ 0x000000: 625*128*16B = 1.28 MB (+96 KB pad) -> ends < 0x150000
    //   xxf @ 0x150000: 40 KB raw norms
    //   xxh @ 0x160000: 40 KB (-0.5*norm) (+24 KB pad)
    //   wsK @ 0x170000: N*NSPLIT*LK u32 = 5.12 MB
    const size_t oXB = 0;
    const size_t oXX = 0x150000;
    const size_t oXH = 0x160000;
    const size_t oWK = 0x170000;
    __bf16* xbA = (__bf16*)((char*)d_ws + oXB);
    float*  xxf = (float*)((char*)d_ws + oXX);
    float*  xxh = (float*)((char*)d_ws + oXH);
    u32*    wsK = (u32*)((char*)d_ws + oWK);

    const int prepThreads = NTILES * 2 * 64 + N;         // 90000
    prep<<<(prepThreads + 255) / 256, 256, 0, stream>>>(x, xbA, xxf, xxh, N);

    long long totalF4 = (long long)out_size / 16;        // 25e6 float4
    int f4PerB = (int)((totalF4 + NCOMP - 1) / NCOMP);   // 39063
    topk_zero_mfma<<<NCOMP, 256, 0, stream>>>(
        xbA, xxh, N, wsK, out, totalF4, f4PerB);

    rescore_scatter<<<NTILES, 64, 0, stream>>>(wsK, x, xxf, out, N);
}

// Round 9
// 413.660 us; speedup vs baseline: 1.3741x; 1.0154x over previous
//
#include <hip/hip_runtime.h>

#define D 64
#define K 5
#define LK 8                  // per-lane / per-split candidate list length
#define GK 12                 // global candidates rescored per row
#define NSPLIT 16
#define NTILES 625            // 10000 / 16 exactly
#define RWAVE 2               // row-tiles (16 rows each) per wave -> 32 rows/wave
#define RBLK 79               // ceil(10000/128) row-blocks (128 rows per block)
#define NCOMP (RBLK * NSPLIT) // 1264 compute blocks (== the whole grid)
typedef unsigned int u32;
typedef unsigned long long u64;
typedef __bf16 bf16x8 __attribute__((ext_vector_type(8)));
typedef float  f32x4v __attribute__((ext_vector_type(4)));

// v_med3_u32 (GCN3+; no HIP builtin)
__device__ __forceinline__ u32 med3u(u32 a, u32 b, u32 c) {
    u32 r;
    asm("v_med3_u32 %0, %1, %2, %3" : "=v"(r) : "v"(a), "v"(b), "v"(c));
    return r;
}

// ---- u32 key: [31:14] = top bits of FULL monotone fp32 map, [13:0] = 0x3FFF-idx
// (== (~idx)&0x3FFF for idx<16384). bigger key == (bigger value, then lower idx).
__device__ __forceinline__ int idx32(u32 key) { return (int)((~key) & 0x3FFFu); }

// exact final key (value, then lower idx)
__device__ __forceinline__ u64 packKV(float v, int idx) {
    u32 u = __float_as_uint(v);
    u ^= ((u32)((int)u >> 31)) | 0x80000000u;
    return ((u64)u << 32) | (u32)(~idx);
}
__device__ __forceinline__ float unpackV(u64 key) {
    u32 hu = (u32)(key >> 32);
    return (hu & 0x80000000u) ? __uint_as_float(hu & 0x7fffffffu)
                              : __uint_as_float(~hu);
}

// branchless merge of two sorted-desc lists, keep first LO into a[]
template<int LO, int LA, int LB, typename T>
__device__ __forceinline__ void mergeKeep(T a[LA], const T b[LB]) {
    T A[LA], B[LB], out[LO];
#pragma unroll
    for (int i = 0; i < LA; ++i) A[i] = a[i];
#pragma unroll
    for (int i = 0; i < LB; ++i) B[i] = b[i];
#pragma unroll
    for (int m = 0; m < LO; ++m) {
        bool ta = A[0] >= B[0];
        out[m] = ta ? A[0] : B[0];
#pragma unroll
        for (int i = 0; i < LA - 1; ++i) A[i] = ta ? A[i + 1] : A[i];
        A[LA - 1] = ta ? (T)0 : A[LA - 1];
#pragma unroll
        for (int i = 0; i < LB - 1; ++i) B[i] = ta ? B[i] : B[i + 1];
        B[LB - 1] = ta ? B[LB - 1] : (T)0;
    }
#pragma unroll
    for (int m = 0; m < LO; ++m) a[m] = out[m];
}

// ---------------------------------------------------------------------------
// Prep: repack x into MFMA-fragment order + row norms (raw and -0.5x for the
// MFMA C-operand fold).
// xbA[tile][khalf][lane][8 bf16]: lane = q*16+r holds x[tile*16+r][kh*32+q*8..+8).
// ---------------------------------------------------------------------------
__global__ __launch_bounds__(256) void prep(
    const float* __restrict__ x, __bf16* __restrict__ xbA,
    float* __restrict__ xxf, float* __restrict__ xxh, int N)
{
    int g = blockIdx.x * 256 + threadIdx.x;
    const int REPACK = NTILES * 2 * 64;          // 80000
    if (g < REPACK) {
        int tile = g >> 7;
        int rem  = g & 127;
        int kh   = rem >> 6;
        int lane = rem & 63;
        int q = lane >> 4, r = lane & 15;
        int row = tile * 16 + r;
        int k0  = kh * 32 + q * 8;
        const float4* p = (const float4*)(x + (size_t)row * D + k0);
        float4 v0 = p[0], v1 = p[1];
        bf16x8 o;
        o[0] = (__bf16)v0.x; o[1] = (__bf16)v0.y; o[2] = (__bf16)v0.z; o[3] = (__bf16)v0.w;
        o[4] = (__bf16)v1.x; o[5] = (__bf16)v1.y; o[6] = (__bf16)v1.z; o[7] = (__bf16)v1.w;
        ((bf16x8*)xbA)[g] = o;
        return;
    }
    int i = g - REPACK;
    if (i >= N) return;
    const float4* p = (const float4*)(x + (size_t)i * D);
    float s = 0.f;
#pragma unroll
    for (int t = 0; t < 16; ++t) {
        float4 v = p[t];
        s += v.x * v.x + v.y * v.y + v.z * v.z + v.w * v.w;
    }
    xxf[i] = s;
    xxh[i] = -0.5f * s;
}

// ---------------------------------------------------------------------------
// Round-9: store-fused zeroing + DOUBLED wave count (RWAVE 4->2).
// r8's grid (2560 waves) capped occupancy at 2.5 waves/SIMD; per CU each
// iteration-round must drain ~40KB of NT stores (~6300 cyc at the per-CU
// write allocation) against only ~1200 cyc of VALU work, so waves sit
// blocked on store drain with nothing else resident -> bursty write stream,
// ~4 TB/s effective. 1264 blocks / 5056 waves (~4.9/SIMD) keep the write
// pipe continuously fed and hide the stall. 1-deep prefetch (2-deep proven
// null in r8; saves ~24 VGPR -> ~90 VGPR, 5 waves/SIMD pool headroom).
// Costs accepted: A-load L2 traffic x2 (~+13us hidden), issue floor 20->24us.
// Stores: 2 guarded NT per iter + tail drain (f4PerB=19779 -> 78 slots/thread
// needed, 39-40 iters x 2 = 78-80 available; drain covers the exact-fit edge).
// ---------------------------------------------------------------------------
__global__ __launch_bounds__(256) void topk_zero_mfma(
    const __bf16* __restrict__ xbA, const float* __restrict__ xxh, int N,
    u32* __restrict__ wsK, float* __restrict__ outZ, long long totalF4,
    int f4PerB)
{
    const int bx  = blockIdx.x;
    const int tid = threadIdx.x;

    const int split = bx / RBLK;                 // 0..15
    const int rb    = bx - split * RBLK;         // 0..78

    const int lane = tid & 63;
    const int wave = tid >> 6;
    const int l15  = lane & 15;
    const int q    = lane >> 4;                  // col quad
    const int r0   = rb * 128 + wave * 32;       // first of this wave's 32 rows

    // my zero slice [zi, ze) in float4 units
    long long zi = (long long)bx * f4PerB + tid;
    long long ze = (long long)(bx + 1) * f4PerB;
    if (ze > totalF4) ze = totalF4;
    const f32x4v zv = {0.f, 0.f, 0.f, 0.f};

    const bf16x8* fb = (const bf16x8*)xbA;       // fragment base, 128 per tile

    // B fragments: 2 row-tiles (clamped at the table end for tail waves)
    bf16x8 Bf[RWAVE][2];
#pragma unroll
    for (int l = 0; l < RWAVE; ++l) {
        int bt = (r0 >> 4) + l; if (bt > NTILES - 1) bt = NTILES - 1;
        Bf[l][0] = fb[bt * 128 + lane];
        Bf[l][1] = fb[bt * 128 + 64 + lane];
    }

    // pointer-bumped loop state
    const bf16x8* ap = fb + (size_t)split * 128 + lane;
    const float* xhp = xxh + split * 16 + q * 4;
    u32 base16k = 0x3FFFu - (u32)(split * 16 + q * 4);   // 0x3FFF - cbase
    const int apBump = NSPLIT * 128;             // 2048 fragments
    const int xcBump = NSPLIT * 16;              // 256 floats

    u32 L[RWAVE][LK];
#pragma unroll
    for (int l = 0; l < RWAVE; ++l)
#pragma unroll
        for (int m = 0; m < LK; ++m) L[l][m] = 0u;   // 0 < any real packed key

    // 1-deep software pipeline; prefetch overruns <=16 tiles (32 KB) past
    // xbA and ~1 KB past xxh — workspace pads cover both.
    bf16x8 A0 = ap[0];
    bf16x8 A1 = ap[64];
    f32x4v xh = *(const f32x4v*)xhp;

    for (int t = split; t < NTILES; t += NSPLIT) {
        ap += apBump; xhp += xcBump;
        const bf16x8 nA0 = ap[0];
        const bf16x8 nA1 = ap[64];
        const f32x4v nxh = *(const f32x4v*)xhp;

#pragma unroll
        for (int l = 0; l < RWAVE; ++l) {
            f32x4v acc = xh;                      // C init = -0.5*||xj||^2
            acc = __builtin_amdgcn_mfma_f32_16x16x32_bf16(A0, Bf[l][0], acc, 0, 0, 0);
            acc = __builtin_amdgcn_mfma_f32_16x16x32_bf16(A1, Bf[l][1], acc, 0, 0, 0);

            // monotone key map (5 ops) + med3 insertion (8 ops) per candidate
#pragma unroll
            for (int v = 0; v < 4; ++v) {
                u32 u = __float_as_uint(acc[v]);
                u ^= ((u32)((int)u >> 31)) | 0x80000000u;
                u32 key = (u & 0xFFFFC000u) | (base16k - (u32)v);
                u32 n0 = max(L[l][0], key);
                u32 n1 = med3u(L[l][0], L[l][1], key);
                u32 n2 = med3u(L[l][1], L[l][2], key);
                u32 n3 = med3u(L[l][2], L[l][3], key);
                u32 n4 = med3u(L[l][3], L[l][4], key);
                u32 n5 = med3u(L[l][4], L[l][5], key);
                u32 n6 = med3u(L[l][5], L[l][6], key);
                u32 n7 = med3u(L[l][6], L[l][7], key);
                L[l][0]=n0; L[l][1]=n1; L[l][2]=n2; L[l][3]=n3;
                L[l][4]=n4; L[l][5]=n5; L[l][6]=n6; L[l][7]=n7;
            }
        }
        base16k -= (u32)xcBump;
        A0 = nA0; A1 = nA1; xh = nxh;

        // zero-stream slice: 2 guarded NT stores (512 f4 per block-iter)
#pragma unroll
        for (int j = 0; j < 2; ++j) {
            if (zi < ze)
                __builtin_nontemporal_store(zv, (f32x4v*)(outZ + 4 * zi));
            zi += 256;
        }
    }

    // tail drain (covers the exact-fit boundary between slots and slice)
    while (zi < ze) {
        __builtin_nontemporal_store(zv, (f32x4v*)(outZ + 4 * zi));
        zi += 256;
    }

    // per row-tile: butterfly merge across the 4 quads sharing a row, then
    // lane<16 writes that row's split-list to wsK
#pragma unroll
    for (int l = 0; l < RWAVE; ++l) {
#pragma unroll
        for (int mask = 16; mask <= 32; mask <<= 1) {
            u32 P[LK];
#pragma unroll
            for (int m = 0; m < LK; ++m) P[m] = (u32)__shfl_xor((int)L[l][m], mask);
            mergeKeep<LK, LK, LK, u32>(L[l], P);
        }
        if (lane < 16) {
            int row = r0 + l * 16 + l15;
            if (row < N) {
                u32* dst = wsK + ((size_t)row * NSPLIT + split) * LK;
#pragma unroll
                for (int m = 0; m < LK; ++m) dst[m] = L[l][m];
            }
        }
    }
}

// ---------------------------------------------------------------------------
// One wave per block, 16 rows per block (625 blocks): 4 lanes per row.
// Each lane merges 4 split-lists (u32); 2 shfl_xor butterflies give the
// global bf16-top-12. Each lane rescores 3 candidates in exact fp32; final
// top-5 via exact packed-u64 butterfly (== reference tie-break). Lane 0 of
// each row does the symmetric atomic scatter.
// ---------------------------------------------------------------------------
__global__ __launch_bounds__(64) void rescore_scatter(
    const u32* __restrict__ wsK, const float* __restrict__ x, const float* __restrict__ xxf,
    float* __restrict__ out, int N)
{
    const int lane = threadIdx.x & 63;
    const int sub  = lane & 3;
    const int row  = blockIdx.x * 16 + (lane >> 2);
    const bool vrow = (row < N);
    const int rr = vrow ? row : 0;

    // merge my 4 lists, then butterfly to global top-12
    u32 cur[GK];
    {
        const u32* Lp = wsK + ((size_t)rr * NSPLIT + 4 * sub) * LK;
#pragma unroll
        for (int m = 0; m < LK; ++m) cur[m] = Lp[m];
#pragma unroll
        for (int m = LK; m < GK; ++m) cur[m] = 0u;
#pragma unroll
        for (int l = 1; l < 4; ++l) {
            u32 b[LK];
#pragma unroll
            for (int m = 0; m < LK; ++m) b[m] = Lp[l * LK + m];
            mergeKeep<GK, GK, LK, u32>(cur, b);
        }
    }
#pragma unroll
    for (int mask = 1; mask <= 2; mask <<= 1) {
        u32 P[GK];
#pragma unroll
        for (int m = 0; m < GK; ++m) P[m] = (u32)__shfl_xor((int)cur[m], mask);
        mergeKeep<GK, GK, GK, u32>(cur, P);
    }

    // exact fp32 rescore of my 3 candidates
    const float nxi = xxf[rr];
    int   cj[3]; bool cval[3];
    float d[3] = {0.f, 0.f, 0.f};
    const f32x4v* pj[3];
#pragma unroll
    for (int c = 0; c < 3; ++c) {
        int j = idx32(cur[sub * 3 + c]);
        cval[c] = (j < N) && (cur[sub * 3 + c] != 0u);
        cj[c] = cval[c] ? j : 0;
        pj[c] = (const f32x4v*)(x + (size_t)cj[c] * D);
    }
    const f32x4v* xip = (const f32x4v*)(x + (size_t)rr * D);
#pragma unroll
    for (int t = 0; t < 16; ++t) {
        const f32x4v xv = xip[t];
#pragma unroll
        for (int c = 0; c < 3; ++c) {
            const f32x4v pv = pj[c][t];
            d[c] = fmaf(xv[0], pv[0], d[c]);
            d[c] = fmaf(xv[1], pv[1], d[c]);
            d[c] = fmaf(xv[2], pv[2], d[c]);
            d[c] = fmaf(xv[3], pv[3], d[c]);
        }
    }
    u64 F[K];
#pragma unroll
    for (int c = 0; c < 3; ++c) {
        float val = 2.f * d[c] - nxi - xxf[cj[c]];
        F[c] = cval[c] ? packKV(val, cj[c]) : 0ull;
    }
    F[3] = 0ull; F[4] = 0ull;
    // sort first 3 desc
    { u64 a0=F[0],a1=F[1],a2=F[2];
      if (a0 < a1) { u64 t0=a0; a0=a1; a1=t0; }
      if (a1 < a2) { u64 t0=a1; a1=a2; a2=t0; }
      if (a0 < a1) { u64 t0=a0; a0=a1; a1=t0; }
      F[0]=a0; F[1]=a1; F[2]=a2; }
#pragma unroll
    for (int mask = 1; mask <= 2; mask <<= 1) {
        u64 P[K];
#pragma unroll
        for (int m = 0; m < K; ++m) P[m] = __shfl_xor(F[m], mask);
        mergeKeep<K, K, K, u64>(F, P);
    }

    if (sub == 0 && vrow) {
#pragma unroll
        for (int m = 0; m < K; ++m) {
            int j = (int)(~(u32)F[m]);
            if ((unsigned)j < (unsigned)N && j != row) {
                float v = unpackV(F[m]);
                atomicAdd(out + (size_t)row * N + j, v);
                atomicAdd(out + (size_t)j * N + row, v);
            }
        }
    }
}

// ---------------------------------------------------------------------------
extern "C" void kernel_launch(void* const* d_in, const int* in_sizes, int n_in,
                              void* d_out, int out_size, void* d_ws, size_t ws_size,
                              hipStream_t stream) {
    const float* x = (const float*)d_in[0];
    const int N = in_sizes[0] / D;          // 10000
    float* out = (float*)d_out;

    // Workspace layout (fixed offsets; pads cover the 1-deep prefetch
    // overrun: <=16 tiles = 32 KB past xbA, ~1 KB past xxh):
    //   xbA @ 0x000000: 625*128*16B = 1.28 MB (+pad)  -> ends < 0x150000
    //   xxf @ 0x150000: 40 KB raw norms
    //   xxh @ 0x160000: 40 KB (-0.5*norm) (+24 KB pad)
    //   wsK @ 0x170000: N*NSPLIT*LK u32 = 5.12 MB
    const size_t oXB = 0;
    const size_t oXX = 0x150000;
    const size_t oXH = 0x160000;
    const size_t oWK = 0x170000;
    __bf16* xbA = (__bf16*)((char*)d_ws + oXB);
    float*  xxf = (float*)((char*)d_ws + oXX);
    float*  xxh = (float*)((char*)d_ws + oXH);
    u32*    wsK = (u32*)((char*)d_ws + oWK);

    const int prepThreads = NTILES * 2 * 64 + N;         // 90000
    prep<<<(prepThreads + 255) / 256, 256, 0, stream>>>(x, xbA, xxf, xxh, N);

    long long totalF4 = (long long)out_size / 16;        // 25e6 float4
    int f4PerB = (int)((totalF4 + NCOMP - 1) / NCOMP);   // 19779
    topk_zero_mfma<<<NCOMP, 256, 0, stream>>>(
        xbA, xxh, N, wsK, out, totalF4, f4PerB);

    rescore_scatter<<<NTILES, 64, 0, stream>>>(wsK, x, xxf, out, N);
}

// Round 10
// 396.725 us; speedup vs baseline: 1.4327x; 1.0427x over previous
//
#include <hip/hip_runtime.h>

#define D 64
#define K 5
#define LK 8                  // per-lane / per-split candidate list length
#define GK 12                 // global candidates rescored per row
#define NSPLIT 16
#define NTILES 625            // 10000 / 16 exactly
#define RWAVE 2               // row-tiles (16 rows each) per wave -> 32 rows/wave
#define RBLK 79               // ceil(10000/128) row-blocks (128 rows per block)
#define NCOMP (RBLK * NSPLIT) // 1264 compute blocks (== the whole grid)
typedef unsigned int u32;
typedef unsigned long long u64;
typedef __bf16 bf16x8 __attribute__((ext_vector_type(8)));
typedef float  f32x4v __attribute__((ext_vector_type(4)));

// v_med3_u32 (GCN3+; no HIP builtin)
__device__ __forceinline__ u32 med3u(u32 a, u32 b, u32 c) {
    u32 r;
    asm("v_med3_u32 %0, %1, %2, %3" : "=v"(r) : "v"(a), "v"(b), "v"(c));
    return r;
}

// ---- u32 key: [31:14] = top bits of FULL monotone fp32 map, [13:0] = 0x3FFF-idx
// (== (~idx)&0x3FFF for idx<16384). bigger key == (bigger value, then lower idx).
__device__ __forceinline__ int idx32(u32 key) { return (int)((~key) & 0x3FFFu); }

// exact final key (value, then lower idx)
__device__ __forceinline__ u64 packKV(float v, int idx) {
    u32 u = __float_as_uint(v);
    u ^= ((u32)((int)u >> 31)) | 0x80000000u;
    return ((u64)u << 32) | (u32)(~idx);
}
__device__ __forceinline__ float unpackV(u64 key) {
    u32 hu = (u32)(key >> 32);
    return (hu & 0x80000000u) ? __uint_as_float(hu & 0x7fffffffu)
                              : __uint_as_float(~hu);
}

// branchless merge of two sorted-desc lists, keep first LO into a[]
template<int LO, int LA, int LB, typename T>
__device__ __forceinline__ void mergeKeep(T a[LA], const T b[LB]) {
    T A[LA], B[LB], out[LO];
#pragma unroll
    for (int i = 0; i < LA; ++i) A[i] = a[i];
#pragma unroll
    for (int i = 0; i < LB; ++i) B[i] = b[i];
#pragma unroll
    for (int m = 0; m < LO; ++m) {
        bool ta = A[0] >= B[0];
        out[m] = ta ? A[0] : B[0];
#pragma unroll
        for (int i = 0; i < LA - 1; ++i) A[i] = ta ? A[i + 1] : A[i];
        A[LA - 1] = ta ? (T)0 : A[LA - 1];
#pragma unroll
        for (int i = 0; i < LB - 1; ++i) B[i] = ta ? B[i] : B[i + 1];
        B[LB - 1] = ta ? B[LB - 1] : (T)0;
    }
#pragma unroll
    for (int m = 0; m < LO; ++m) a[m] = out[m];
}

// ---------------------------------------------------------------------------
// Prep: repack x into MFMA-fragment order + row norms (raw and -0.5x for the
// MFMA C-operand fold).
// xbA[tile][khalf][lane][8 bf16]: lane = q*16+r holds x[tile*16+r][kh*32+q*8..+8).
// ---------------------------------------------------------------------------
__global__ __launch_bounds__(256) void prep(
    const float* __restrict__ x, __bf16* __restrict__ xbA,
    float* __restrict__ xxf, float* __restrict__ xxh, int N)
{
    int g = blockIdx.x * 256 + threadIdx.x;
    const int REPACK = NTILES * 2 * 64;          // 80000
    if (g < REPACK) {
        int tile = g >> 7;
        int rem  = g & 127;
        int kh   = rem >> 6;
        int lane = rem & 63;
        int q = lane >> 4, r = lane & 15;
        int row = tile * 16 + r;
        int k0  = kh * 32 + q * 8;
        const float4* p = (const float4*)(x + (size_t)row * D + k0);
        float4 v0 = p[0], v1 = p[1];
        bf16x8 o;
        o[0] = (__bf16)v0.x; o[1] = (__bf16)v0.y; o[2] = (__bf16)v0.z; o[3] = (__bf16)v0.w;
        o[4] = (__bf16)v1.x; o[5] = (__bf16)v1.y; o[6] = (__bf16)v1.z; o[7] = (__bf16)v1.w;
        ((bf16x8*)xbA)[g] = o;
        return;
    }
    int i = g - REPACK;
    if (i >= N) return;
    const float4* p = (const float4*)(x + (size_t)i * D);
    float s = 0.f;
#pragma unroll
    for (int t = 0; t < 16; ++t) {
        float4 v = p[t];
        s += v.x * v.x + v.y * v.y + v.z * v.z + v.w * v.w;
    }
    xxf[i] = s;
    xxh[i] = -0.5f * s;
}

// ---------------------------------------------------------------------------
// Round-10: store-fused zeroing with PLAIN stores, issued right after the
// MFMAs (before the insert VALU burst).
// Rationale: the only write streams measured at >=6 TB/s on this machine
// (harness fill, r2's dedicated zero) use plain stores; every NT config
// implied <=5 TB/s. NT bypasses L2 -> the HBM write queue sees the raw
// 2-stores-per-iteration pulse train from compute waves and backs up into
// waitcnt stalls. Plain stores land in L2 (400MB >> 32MB L2 so steady-state
// HBM rate is identical) but L2 acts as an elastic buffer decoupling wave
// issue from HBM drain. Store issue placed before the ~104-cyc insert VALU
// block so the write engine starts each iteration's drain under the compute.
// Everything else identical to r9: 1264 blocks (~4.9 waves/SIMD), RWAVE=2,
// 1-deep prefetch, med3 insert network, tail drain.
// ---------------------------------------------------------------------------
__global__ __launch_bounds__(256) void topk_zero_mfma(
    const __bf16* __restrict__ xbA, const float* __restrict__ xxh, int N,
    u32* __restrict__ wsK, float* __restrict__ outZ, long long totalF4,
    int f4PerB)
{
    const int bx  = blockIdx.x;
    const int tid = threadIdx.x;

    const int split = bx / RBLK;                 // 0..15
    const int rb    = bx - split * RBLK;         // 0..78

    const int lane = tid & 63;
    const int wave = tid >> 6;
    const int l15  = lane & 15;
    const int q    = lane >> 4;                  // col quad
    const int r0   = rb * 128 + wave * 32;       // first of this wave's 32 rows

    // my zero slice [zi, ze) in float4 units
    long long zi = (long long)bx * f4PerB + tid;
    long long ze = (long long)(bx + 1) * f4PerB;
    if (ze > totalF4) ze = totalF4;
    const f32x4v zv = {0.f, 0.f, 0.f, 0.f};

    const bf16x8* fb = (const bf16x8*)xbA;       // fragment base, 128 per tile

    // B fragments: 2 row-tiles (clamped at the table end for tail waves)
    bf16x8 Bf[RWAVE][2];
#pragma unroll
    for (int l = 0; l < RWAVE; ++l) {
        int bt = (r0 >> 4) + l; if (bt > NTILES - 1) bt = NTILES - 1;
        Bf[l][0] = fb[bt * 128 + lane];
        Bf[l][1] = fb[bt * 128 + 64 + lane];
    }

    // pointer-bumped loop state
    const bf16x8* ap = fb + (size_t)split * 128 + lane;
    const float* xhp = xxh + split * 16 + q * 4;
    u32 base16k = 0x3FFFu - (u32)(split * 16 + q * 4);   // 0x3FFF - cbase
    const int apBump = NSPLIT * 128;             // 2048 fragments
    const int xcBump = NSPLIT * 16;              // 256 floats

    u32 L[RWAVE][LK];
#pragma unroll
    for (int l = 0; l < RWAVE; ++l)
#pragma unroll
        for (int m = 0; m < LK; ++m) L[l][m] = 0u;   // 0 < any real packed key

    // 1-deep software pipeline; prefetch overruns <=16 tiles (32 KB) past
    // xbA and ~1 KB past xxh — workspace pads cover both.
    bf16x8 A0 = ap[0];
    bf16x8 A1 = ap[64];
    f32x4v xh = *(const f32x4v*)xhp;

    for (int t = split; t < NTILES; t += NSPLIT) {
        ap += apBump; xhp += xcBump;
        const bf16x8 nA0 = ap[0];
        const bf16x8 nA1 = ap[64];
        const f32x4v nxh = *(const f32x4v*)xhp;

        // zero-stream slice: 2 guarded PLAIN stores issued before the insert
        // burst (write drain overlaps the VALU work below)
#pragma unroll
        for (int j = 0; j < 2; ++j) {
            if (zi < ze)
                *(f32x4v*)(outZ + 4 * zi) = zv;
            zi += 256;
        }

#pragma unroll
        for (int l = 0; l < RWAVE; ++l) {
            f32x4v acc = xh;                      // C init = -0.5*||xj||^2
            acc = __builtin_amdgcn_mfma_f32_16x16x32_bf16(A0, Bf[l][0], acc, 0, 0, 0);
            acc = __builtin_amdgcn_mfma_f32_16x16x32_bf16(A1, Bf[l][1], acc, 0, 0, 0);

            // monotone key map (5 ops) + med3 insertion (8 ops) per candidate
#pragma unroll
            for (int v = 0; v < 4; ++v) {
                u32 u = __float_as_uint(acc[v]);
                u ^= ((u32)((int)u >> 31)) | 0x80000000u;
                u32 key = (u & 0xFFFFC000u) | (base16k - (u32)v);
                u32 n0 = max(L[l][0], key);
                u32 n1 = med3u(L[l][0], L[l][1], key);
                u32 n2 = med3u(L[l][1], L[l][2], key);
                u32 n3 = med3u(L[l][2], L[l][3], key);
                u32 n4 = med3u(L[l][3], L[l][4], key);
                u32 n5 = med3u(L[l][4], L[l][5], key);
                u32 n6 = med3u(L[l][5], L[l][6], key);
                u32 n7 = med3u(L[l][6], L[l][7], key);
                L[l][0]=n0; L[l][1]=n1; L[l][2]=n2; L[l][3]=n3;
                L[l][4]=n4; L[l][5]=n5; L[l][6]=n6; L[l][7]=n7;
            }
        }
        base16k -= (u32)xcBump;
        A0 = nA0; A1 = nA1; xh = nxh;
    }

    // tail drain (covers the exact-fit boundary between slots and slice)
    while (zi < ze) {
        *(f32x4v*)(outZ + 4 * zi) = zv;
        zi += 256;
    }

    // per row-tile: butterfly merge across the 4 quads sharing a row, then
    // lane<16 writes that row's split-list to wsK
#pragma unroll
    for (int l = 0; l < RWAVE; ++l) {
#pragma unroll
        for (int mask = 16; mask <= 32; mask <<= 1) {
            u32 P[LK];
#pragma unroll
            for (int m = 0; m < LK; ++m) P[m] = (u32)__shfl_xor((int)L[l][m], mask);
            mergeKeep<LK, LK, LK, u32>(L[l], P);
        }
        if (lane < 16) {
            int row = r0 + l * 16 + l15;
            if (row < N) {
                u32* dst = wsK + ((size_t)row * NSPLIT + split) * LK;
#pragma unroll
                for (int m = 0; m < LK; ++m) dst[m] = L[l][m];
            }
        }
    }
}

// ---------------------------------------------------------------------------
// One wave per block, 16 rows per block (625 blocks): 4 lanes per row.
// Each lane merges 4 split-lists (u32); 2 shfl_xor butterflies give the
// global bf16-top-12. Each lane rescores 3 candidates in exact fp32; final
// top-5 via exact packed-u64 butterfly (== reference tie-break). Lane 0 of
// each row does the symmetric atomic scatter.
// ---------------------------------------------------------------------------
__global__ __launch_bounds__(64) void rescore_scatter(
    const u32* __restrict__ wsK, const float* __restrict__ x, const float* __restrict__ xxf,
    float* __restrict__ out, int N)
{
    const int lane = threadIdx.x & 63;
    const int sub  = lane & 3;
    const int row  = blockIdx.x * 16 + (lane >> 2);
    const bool vrow = (row < N);
    const int rr = vrow ? row : 0;

    // merge my 4 lists, then butterfly to global top-12
    u32 cur[GK];
    {
        const u32* Lp = wsK + ((size_t)rr * NSPLIT + 4 * sub) * LK;
#pragma unroll
        for (int m = 0; m < LK; ++m) cur[m] = Lp[m];
#pragma unroll
        for (int m = LK; m < GK; ++m) cur[m] = 0u;
#pragma unroll
        for (int l = 1; l < 4; ++l) {
            u32 b[LK];
#pragma unroll
            for (int m = 0; m < LK; ++m) b[m] = Lp[l * LK + m];
            mergeKeep<GK, GK, LK, u32>(cur, b);
        }
    }
#pragma unroll
    for (int mask = 1; mask <= 2; mask <<= 1) {
        u32 P[GK];
#pragma unroll
        for (int m = 0; m < GK; ++m) P[m] = (u32)__shfl_xor((int)cur[m], mask);
        mergeKeep<GK, GK, GK, u32>(cur, P);
    }

    // exact fp32 rescore of my 3 candidates
    const float nxi = xxf[rr];
    int   cj[3]; bool cval[3];
    float d[3] = {0.f, 0.f, 0.f};
    const f32x4v* pj[3];
#pragma unroll
    for (int c = 0; c < 3; ++c) {
        int j = idx32(cur[sub * 3 + c]);
        cval[c] = (j < N) && (cur[sub * 3 + c] != 0u);
        cj[c] = cval[c] ? j : 0;
        pj[c] = (const f32x4v*)(x + (size_t)cj[c] * D);
    }
    const f32x4v* xip = (const f32x4v*)(x + (size_t)rr * D);
#pragma unroll
    for (int t = 0; t < 16; ++t) {
        const f32x4v xv = xip[t];
#pragma unroll
        for (int c = 0; c < 3; ++c) {
            const f32x4v pv = pj[c][t];
            d[c] = fmaf(xv[0], pv[0], d[c]);
            d[c] = fmaf(xv[1], pv[1], d[c]);
            d[c] = fmaf(xv[2], pv[2], d[c]);
            d[c] = fmaf(xv[3], pv[3], d[c]);
        }
    }
    u64 F[K];
#pragma unroll
    for (int c = 0; c < 3; ++c) {
        float val = 2.f * d[c] - nxi - xxf[cj[c]];
        F[c] = cval[c] ? packKV(val, cj[c]) : 0ull;
    }
    F[3] = 0ull; F[4] = 0ull;
    // sort first 3 desc
    { u64 a0=F[0],a1=F[1],a2=F[2];
      if (a0 < a1) { u64 t0=a0; a0=a1; a1=t0; }
      if (a1 < a2) { u64 t0=a1; a1=a2; a2=t0; }
      if (a0 < a1) { u64 t0=a0; a0=a1; a1=t0; }
      F[0]=a0; F[1]=a1; F[2]=a2; }
#pragma unroll
    for (int mask = 1; mask <= 2; mask <<= 1) {
        u64 P[K];
#pragma unroll
        for (int m = 0; m < K; ++m) P[m] = __shfl_xor(F[m], mask);
        mergeKeep<K, K, K, u64>(F, P);
    }

    if (sub == 0 && vrow) {
#pragma unroll
        for (int m = 0; m < K; ++m) {
            int j = (int)(~(u32)F[m]);
            if ((unsigned)j < (unsigned)N && j != row) {
                float v = unpackV(F[m]);
                atomicAdd(out + (size_t)row * N + j, v);
                atomicAdd(out + (size_t)j * N + row, v);
            }
        }
    }
}

// ---------------------------------------------------------------------------
extern "C" void kernel_launch(void* const* d_in, const int* in_sizes, int n_in,
                              void* d_out, int out_size, void* d_ws, size_t ws_size,
                              hipStream_t stream) {
    const float* x = (const float*)d_in[0];
    const int N = in_sizes[0] / D;          // 10000
    float* out = (float*)d_out;

    // Workspace layout (fixed offsets; pads cover the 1-deep prefetch
    // overrun: <=16 tiles = 32 KB past xbA, ~1 KB past xxh):
    //   xbA @ 0x000000: 625*128*16B = 1.28 MB (+pad)  -> ends < 0x150000
    //   xxf @ 0x150000: 40 KB raw norms
    //   xxh @ 0x160000: 40 KB (-0.5*norm) (+24 KB pad)
    //   wsK @ 0x170000: N*NSPLIT*LK u32 = 5.12 MB
    const size_t oXB = 0;
    const size_t oXX = 0x150000;
    const size_t oXH = 0x160000;
    const size_t oWK = 0x170000;
    __bf16* xbA = (__bf16*)((char*)d_ws + oXB);
    float*  xxf = (float*)((char*)d_ws + oXX);
    float*  xxh = (float*)((char*)d_ws + oXH);
    u32*    wsK = (u32*)((char*)d_ws + oWK);

    const int prepThreads = NTILES * 2 * 64 + N;         // 90000
    prep<<<(prepThreads + 255) / 256, 256, 0, stream>>>(x, xbA, xxf, xxh, N);

    long long totalF4 = (long long)out_size / 16;        // 25e6 float4
    int f4PerB = (int)((totalF4 + NCOMP - 1) / NCOMP);   // 19779
    topk_zero_mfma<<<NCOMP, 256, 0, stream>>>(
        xbA, xxh, N, wsK, out, totalF4, f4PerB);

    rescore_scatter<<<NTILES, 64, 0, stream>>>(wsK, x, xxf, out, N);
}